// Round 5
// baseline (1640.737 us; speedup 1.0000x reference)
//
#include <hip/hip_runtime.h>

#define DD 64        // embedding dim
#define BROWS 256    // destination rows per bucket
#define BSHIFT 8     // log2(BROWS)

static inline size_t align16(size_t x) { return (x + 15) & ~(size_t)15; }

__device__ __forceinline__ unsigned bf16rn(float f) {
    unsigned u = __float_as_uint(f);
    return (u + 0x7fffu + ((u >> 16) & 1u)) >> 16;   // RNE
}

// ---------------- pass 1: bucket histogram (social rows [0,U), inter rows [U,2U)) ----------------
__global__ __launch_bounds__(256) void bhist(
    const int* __restrict__ srows, const int* __restrict__ irows,
    int* __restrict__ bcnt, int ES, int EI, int U)
{
    int e = blockIdx.x * 256 + threadIdx.x;
    int row;
    if (e < ES) row = srows[e];
    else if (e < ES + EI) row = U + irows[e - ES];
    else return;
    atomicAdd(&bcnt[row >> BSHIFT], 1);
}

// ---------------- generic scan helpers ----------------
__global__ __launch_bounds__(256) void scan_partial(
    const int* __restrict__ in, int* __restrict__ out, int* __restrict__ bsums, int n)
{
    __shared__ int sh[256];
    int base = blockIdx.x * 2048 + threadIdx.x * 8;
    int v[8];
    int tsum = 0;
    #pragma unroll
    for (int j = 0; j < 8; ++j) {
        int idx = base + j;
        int x = (idx < n) ? in[idx] : 0;
        v[j] = tsum;
        tsum += x;
    }
    sh[threadIdx.x] = tsum;
    __syncthreads();
    for (int off = 1; off < 256; off <<= 1) {
        int t = (threadIdx.x >= off) ? sh[threadIdx.x - off] : 0;
        __syncthreads();
        sh[threadIdx.x] += t;
        __syncthreads();
    }
    int texc = sh[threadIdx.x] - tsum;
    #pragma unroll
    for (int j = 0; j < 8; ++j) {
        int idx = base + j;
        if (idx < n) out[idx] = texc + v[j];
    }
    if (threadIdx.x == 255) bsums[blockIdx.x] = sh[255];
}

__global__ void scan_top(int* bsums, int nb, int* ptr, int n)
{
    int run = 0;
    for (int i = 0; i < nb; ++i) { int t = bsums[i]; bsums[i] = run; run += t; }
    ptr[n] = run;
}

__global__ __launch_bounds__(256) void scan_add2(
    int* __restrict__ out, int* __restrict__ cursor, const int* __restrict__ bsums, int n)
{
    int i = blockIdx.x * 256 + threadIdx.x;
    if (i < n) { int v = out[i] + bsums[i >> 11]; out[i] = v; cursor[i] = v; }
}

// ---------------- phase A: scatter edges into bucket-contiguous regions ----------------
// payload: .x = (row_lo << 17) | col   (row_lo 8b, col <= 17b), .y = fp32 val bits
__global__ __launch_bounds__(256) void phaseA(
    const int* __restrict__ srows, const int* __restrict__ scols, const float* __restrict__ svals,
    const int* __restrict__ irows, const int* __restrict__ icols, const float* __restrict__ ivals,
    int* __restrict__ bcur, uint2* __restrict__ bedges, int ES, int EI, int U)
{
    int e = blockIdx.x * 256 + threadIdx.x;
    int row, col; unsigned val;
    if (e < ES) { row = srows[e]; col = scols[e]; val = __float_as_uint(svals[e]); }
    else if (e < ES + EI) {
        int i = e - ES;
        row = U + irows[i]; col = icols[i]; val = __float_as_uint(ivals[i]);
    } else return;
    int slot = atomicAdd(&bcur[row >> BSHIFT], 1);
    bedges[slot] = make_uint2(((unsigned)(row & (BROWS - 1)) << 17) | (unsigned)col, val);
}

// ---------------- phase B: per-bucket CSR finalize (row_ptr + ordered edges) ----------------
__global__ __launch_bounds__(256) void bucket_csr(
    const uint2* __restrict__ bedges, const int* __restrict__ bptr,
    int* __restrict__ row_ptr, uint2* __restrict__ edges, int n2, int NB)
{
    __shared__ int cnt[BROWS];
    __shared__ int sh[BROWS];
    __shared__ int cur[BROWS];
    const int b = blockIdx.x;
    const int t = threadIdx.x;
    const int s = bptr[b], e = bptr[b + 1];

    cnt[t] = 0;
    __syncthreads();
    for (int i = s + t; i < e; i += 256) atomicAdd(&cnt[bedges[i].x >> 17], 1);
    __syncthreads();

    int c = cnt[t];
    sh[t] = c;
    __syncthreads();
    for (int off = 1; off < 256; off <<= 1) {
        int v = (t >= off) ? sh[t - off] : 0;
        __syncthreads();
        sh[t] += v;
        __syncthreads();
    }
    int excl = sh[t] - c;
    cur[t] = s + excl;
    int gr = b * BROWS + t;
    if (gr < n2) row_ptr[gr] = s + excl;
    if (b == NB - 1 && t == 0) row_ptr[n2] = e;   // == Etot
    __syncthreads();

    for (int i = s + t; i < e; i += 256) {
        uint2 ev = bedges[i];
        int r = ev.x >> 17;
        int slot = atomicAdd(&cur[r], 1);
        edges[slot] = make_uint2(ev.x & 0x1FFFFu, ev.y);
    }
}

// ---------------- fp32 -> bf16 table conversion ----------------
__global__ __launch_bounds__(256) void f32_to_bf16_k(
    const float* __restrict__ in, ushort* __restrict__ out, int n8)
{
    int i = blockIdx.x * 256 + threadIdx.x;
    if (i >= n8) return;
    const float4* p = reinterpret_cast<const float4*>(in) + (size_t)i * 2;
    float4 A = p[0], B = p[1];
    uint4 r;
    r.x = bf16rn(A.x) | (bf16rn(A.y) << 16);
    r.y = bf16rn(A.z) | (bf16rn(A.w) << 16);
    r.z = bf16rn(B.x) | (bf16rn(B.y) << 16);
    r.w = bf16rn(B.z) | (bf16rn(B.w) << 16);
    reinterpret_cast<uint4*>(out)[i] = r;
}

// ---------------- SpMM (CSR row-gather, bf16 source, fp32 accumulate) ----------------
template <bool ADD>
__global__ __launch_bounds__(256) void spmm_bf16(
    const int* __restrict__ row_ptr, const uint2* __restrict__ edges,
    const ushort* __restrict__ xb,   // bf16 [nx,64]
    float* __restrict__ out, int nrows)
{
    int g    = (blockIdx.x * 256 + threadIdx.x) >> 4;
    int lane = threadIdx.x & 15;
    if (g >= nrows) return;
    int s = row_ptr[g], e = row_ptr[g + 1];
    float4 acc = make_float4(0.f, 0.f, 0.f, 0.f);
    int i = s;
    for (; i + 1 < e; i += 2) {
        uint2 e0 = edges[i], e1 = edges[i + 1];
        uint2 x0 = *reinterpret_cast<const uint2*>(xb + ((size_t)e0.x << 6) + lane * 4);
        uint2 x1 = *reinterpret_cast<const uint2*>(xb + ((size_t)e1.x << 6) + lane * 4);
        float v0 = __uint_as_float(e0.y);
        float v1 = __uint_as_float(e1.y);
        acc.x += v0 * __uint_as_float(x0.x << 16);
        acc.y += v0 * __uint_as_float(x0.x & 0xffff0000u);
        acc.z += v0 * __uint_as_float(x0.y << 16);
        acc.w += v0 * __uint_as_float(x0.y & 0xffff0000u);
        acc.x += v1 * __uint_as_float(x1.x << 16);
        acc.y += v1 * __uint_as_float(x1.x & 0xffff0000u);
        acc.z += v1 * __uint_as_float(x1.y << 16);
        acc.w += v1 * __uint_as_float(x1.y & 0xffff0000u);
    }
    if (i < e) {
        uint2 e0 = edges[i];
        uint2 x0 = *reinterpret_cast<const uint2*>(xb + ((size_t)e0.x << 6) + lane * 4);
        float v0 = __uint_as_float(e0.y);
        acc.x += v0 * __uint_as_float(x0.x << 16);
        acc.y += v0 * __uint_as_float(x0.x & 0xffff0000u);
        acc.z += v0 * __uint_as_float(x0.y << 16);
        acc.w += v0 * __uint_as_float(x0.y & 0xffff0000u);
    }
    float* o = out + ((size_t)g << 6) + lane * 4;
    if (ADD) {
        float4 cur = *reinterpret_cast<const float4*>(o);
        acc.x += cur.x; acc.y += cur.y; acc.z += cur.z; acc.w += cur.w;
    }
    *reinterpret_cast<float4*>(o) = acc;
}

// ---------------- register-tiled concat GEMM ----------------
__global__ __launch_bounds__(256) void gemm2(
    const float* __restrict__ a,     // new_u (spmm result) [U,64]
    const float* __restrict__ b,     // u (prev embedding)  [U,64]
    const float* __restrict__ w,     // [128,64] row-major
    float* __restrict__ outf,        // fp32 out [U,64]
    ushort* __restrict__ outb,       // bf16 out [U,64] or nullptr
    int U)
{
    __shared__ float sIn[64 * 128];
    __shared__ float sWt[64 * 128];
    const int t    = threadIdx.x;
    const int base = blockIdx.x * 64;

    // stage W^T, XOR-swizzled: dw(col,j) = col*128 + ((((j>>2)^((col>>1)&7))<<2) | (j&3))
    for (int i = t; i < 2048; i += 256) {
        int j  = i >> 4;
        int c4 = (i & 15) << 2;
        float4 wv = reinterpret_cast<const float4*>(w)[i];
        float vv[4] = { wv.x, wv.y, wv.z, wv.w };
        #pragma unroll
        for (int e2 = 0; e2 < 4; ++e2) {
            int col = c4 + e2;
            int dw  = col * 128 + ((((j >> 2) ^ ((col >> 1) & 7)) << 2) | (j & 3));
            sWt[dw] = vv[e2];
        }
    }
    // stage inputs: sIn[row][0..63] = a-row, [64..127] = b-row
    for (int i = t; i < 2048; i += 256) {
        int row  = i >> 5;
        int q    = i & 31;
        int grow = base + row;
        float4 v = make_float4(0.f, 0.f, 0.f, 0.f);
        int qq = q & 15;
        if (grow < U) {
            const float* src = (q < 16) ? a : b;
            v = *reinterpret_cast<const float4*>(src + ((size_t)grow << 6) + qq * 4);
        }
        int off = (q < 16) ? qq * 4 : 64 + qq * 4;
        *reinterpret_cast<float4*>(&sIn[row * 128 + off]) = v;
    }
    __syncthreads();

    const int w_ = t >> 6;
    const int l  = t & 63;
    const int h  = l >> 5;
    const int lq = l & 31;
    const int c0 = lq * 2;
    const int rb = w_ * 16 + h * 8;
    const int sw = lq & 7;

    float acc[8][2];
    #pragma unroll
    for (int r = 0; r < 8; ++r) { acc[r][0] = 0.f; acc[r][1] = 0.f; }

    #pragma unroll 4
    for (int j4 = 0; j4 < 32; ++j4) {
        int so = ((j4 ^ sw) << 2);
        float4 w40 = *reinterpret_cast<const float4*>(&sWt[c0 * 128 + so]);
        float4 w41 = *reinterpret_cast<const float4*>(&sWt[(c0 + 1) * 128 + so]);
        #pragma unroll
        for (int r = 0; r < 8; ++r) {
            float4 iv = *reinterpret_cast<const float4*>(&sIn[(rb + r) * 128 + j4 * 4]);
            acc[r][0] += iv.x * w40.x + iv.y * w40.y + iv.z * w40.z + iv.w * w40.w;
            acc[r][1] += iv.x * w41.x + iv.y * w41.y + iv.z * w41.z + iv.w * w41.w;
        }
    }

    #pragma unroll
    for (int r = 0; r < 8; ++r) {
        int grow = base + rb + r;
        if (grow < U) {
            *reinterpret_cast<float2*>(&outf[((size_t)grow << 6) + c0]) =
                make_float2(acc[r][0], acc[r][1]);
            if (outb) {
                unsigned pk = bf16rn(acc[r][0]) | (bf16rn(acc[r][1]) << 16);
                *reinterpret_cast<unsigned*>(outb + ((size_t)grow << 6) + c0) = pk;
            }
        }
    }
}

extern "C" void kernel_launch(void* const* d_in, const int* in_sizes, int n_in,
                              void* d_out, int out_size, void* d_ws, size_t ws_size,
                              hipStream_t stream)
{
    const float* user_emb    = (const float*)d_in[0];
    const float* item_emb    = (const float*)d_in[1];
    const float* weights     = (const float*)d_in[2];
    const float* social_vals = (const float*)d_in[3];
    const float* inter_vals  = (const float*)d_in[4];
    const int*   social_rows = (const int*)d_in[5];
    const int*   social_cols = (const int*)d_in[6];
    const int*   inter_rows  = (const int*)d_in[7];
    const int*   inter_cols  = (const int*)d_in[8];

    const int D  = DD;
    const int U  = in_sizes[0] / D;
    const int I  = in_sizes[1] / D;
    const int L  = in_sizes[2] / (2 * D * D);
    const int ES = in_sizes[3];
    const int EI = in_sizes[4];

    float* out      = (float*)d_out;           // final_u [U, D]
    float* out_item = out + (size_t)U * D;     // item_emb passthrough [I, D]

    // ---- workspace layout ----
    char* p = (char*)d_ws;
    size_t off = 0;
    auto take = [&](size_t bytes) { char* r = p + off; off += align16(bytes); return r; };

    const int n2   = 2 * U;
    const int NB   = (n2 + BROWS - 1) / BROWS;
    const int Etot = ES + EI;

    int*    row_ptr = (int*)take((size_t)(n2 + 1) * sizeof(int));
    int*    bptr    = (int*)take((size_t)(NB + 1) * sizeof(int));
    int*    bcnt    = (int*)take((size_t)NB * sizeof(int));
    int*    bcur    = (int*)take((size_t)NB * sizeof(int));
    int*    bsums   = (int*)take(1024 * sizeof(int));
    uint2*  edges   = (uint2*)take((size_t)Etot * sizeof(uint2));
    ushort* ubf     = (ushort*)take((size_t)U * D * sizeof(ushort));
    ushort* ibf     = (ushort*)take((size_t)I * D * sizeof(ushort));
    float*  tmpA    = (float*)take((size_t)U * D * sizeof(float));
    float*  uB      = (float*)take((size_t)U * D * sizeof(float));

    // bedges aliases tmpA: dead before the first spmm writes tmpA (stream-ordered)
    uint2* bedges = (uint2*)tmpA;

    // ---- bucketed CSR build ----
    hipMemsetAsync(bcnt, 0, (size_t)NB * sizeof(int), stream);
    bhist<<<(Etot + 255) / 256, 256, 0, stream>>>(social_rows, inter_rows, bcnt, ES, EI, U);
    const int nb = (NB + 2047) / 2048;
    scan_partial<<<nb, 256, 0, stream>>>(bcnt, bptr, bsums, NB);
    scan_top<<<1, 1, 0, stream>>>(bsums, nb, bptr, NB);
    scan_add2<<<(NB + 255) / 256, 256, 0, stream>>>(bptr, bcur, bsums, NB);
    phaseA<<<(Etot + 255) / 256, 256, 0, stream>>>(
        social_rows, social_cols, social_vals,
        inter_rows, inter_cols, inter_vals,
        bcur, bedges, ES, EI, U);
    bucket_csr<<<NB, 256, 0, stream>>>(bedges, bptr, row_ptr, edges, n2, NB);

    // ---- bf16 gather tables ----
    const int u8 = U * D / 8, i8 = I * D / 8;
    f32_to_bf16_k<<<(u8 + 255) / 256, 256, 0, stream>>>(user_emb, ubf, u8);
    f32_to_bf16_k<<<(i8 + 255) / 256, 256, 0, stream>>>(item_emb, ibf, i8);

    // ---- layers ----
    const int spmm_grid = ((U * 16) + 255) / 256;
    const int gemm_grid = (U + 63) / 64;
    const float* uprev = user_emb;
    for (int k = 0; k < L; ++k) {
        const float* wk = weights + (size_t)k * 2 * D * D;
        spmm_bf16<false><<<spmm_grid, 256, 0, stream>>>(row_ptr, edges, ubf, tmpA, U);
        if (k == L - 1) {
            gemm2<<<gemm_grid, 256, 0, stream>>>(tmpA, uprev, wk, out, (ushort*)nullptr, U);
        } else {
            gemm2<<<gemm_grid, 256, 0, stream>>>(tmpA, uprev, wk, uB, ubf, U);
            uprev = uB;
        }
    }

    // final_u += A_inter @ item_emb (bf16 gather, fp32 accumulate into d_out)
    spmm_bf16<true><<<spmm_grid, 256, 0, stream>>>(row_ptr + U, edges, ibf, out, U);

    // output 1: item_emb passthrough
    hipMemcpyAsync(out_item, item_emb, (size_t)I * D * sizeof(float),
                   hipMemcpyDeviceToDevice, stream);
}

// Round 6
// 479.056 us; speedup vs baseline: 3.4249x; 3.4249x over previous
//
#include <hip/hip_runtime.h>

#define DD 64        // embedding dim
#define BROWS 16     // destination rows per bucket
#define BSHIFT 4     // log2(BROWS)

static inline size_t align16(size_t x) { return (x + 15) & ~(size_t)15; }

__device__ __forceinline__ unsigned bf16rn(float f) {
    unsigned u = __float_as_uint(f);
    return (u + 0x7fffu + ((u >> 16) & 1u)) >> 16;   // RNE
}

// ---------------- row-level histogram (social rows [0,U), inter rows [U,2U)) ----------------
__global__ __launch_bounds__(256) void hist_rows(
    const int* __restrict__ srows, const int* __restrict__ irows,
    int* __restrict__ counts, int ES, int EI, int U)
{
    int e = blockIdx.x * 256 + threadIdx.x;
    if (e < ES) atomicAdd(&counts[srows[e]], 1);
    else if (e < ES + EI) atomicAdd(&counts[U + irows[e - ES]], 1);
}

// ---------------- scan helpers ----------------
__global__ __launch_bounds__(256) void scan_partial(
    const int* __restrict__ in, int* __restrict__ out, int* __restrict__ bsums, int n)
{
    __shared__ int sh[256];
    int base = blockIdx.x * 2048 + threadIdx.x * 8;
    int v[8];
    int tsum = 0;
    #pragma unroll
    for (int j = 0; j < 8; ++j) {
        int idx = base + j;
        int x = (idx < n) ? in[idx] : 0;
        v[j] = tsum;
        tsum += x;
    }
    sh[threadIdx.x] = tsum;
    __syncthreads();
    for (int off = 1; off < 256; off <<= 1) {
        int t = (threadIdx.x >= off) ? sh[threadIdx.x - off] : 0;
        __syncthreads();
        sh[threadIdx.x] += t;
        __syncthreads();
    }
    int texc = sh[threadIdx.x] - tsum;
    #pragma unroll
    for (int j = 0; j < 8; ++j) {
        int idx = base + j;
        if (idx < n) out[idx] = texc + v[j];
    }
    if (threadIdx.x == 255) bsums[blockIdx.x] = sh[255];
}

__global__ void scan_top(int* bsums, int nb, int* ptr, int n)
{
    int run = 0;
    for (int i = 0; i < nb; ++i) { int t = bsums[i]; bsums[i] = run; run += t; }
    ptr[n] = run;
}

// add block offsets; also emit bucket cursors bcur[j] = row_ptr[j*BROWS]
__global__ __launch_bounds__(256) void scan_add_bcur(
    int* __restrict__ out, int* __restrict__ bcur, const int* __restrict__ bsums, int n)
{
    int i = blockIdx.x * 256 + threadIdx.x;
    if (i < n) {
        int v = out[i] + bsums[i >> 11];
        out[i] = v;
        if ((i & (BROWS - 1)) == 0) bcur[i >> BSHIFT] = v;
    }
}

// ---------------- phase A: scatter edges into bucket regions (16 rows each) ----------------
// payload: .x = (row_lo << 17) | col   (row_lo 4b, col <= 17b), .y = fp32 val bits
__global__ __launch_bounds__(256) void phaseA(
    const int* __restrict__ srows, const int* __restrict__ scols, const float* __restrict__ svals,
    const int* __restrict__ irows, const int* __restrict__ icols, const float* __restrict__ ivals,
    int* __restrict__ bcur, uint2* __restrict__ bedges, int ES, int EI, int U)
{
    int e = blockIdx.x * 256 + threadIdx.x;
    int row, col; unsigned val;
    if (e < ES) { row = srows[e]; col = scols[e]; val = __float_as_uint(svals[e]); }
    else if (e < ES + EI) {
        int i = e - ES;
        row = U + irows[i]; col = icols[i]; val = __float_as_uint(ivals[i]);
    } else return;
    int slot = atomicAdd(&bcur[row >> BSHIFT], 1);
    bedges[slot] = make_uint2(((unsigned)(row & (BROWS - 1)) << 17) | (unsigned)col, val);
}

// ---------------- phase B: within-bucket finalize to exact CSR slots ----------------
__global__ __launch_bounds__(128) void bucket_fin(
    const uint2* __restrict__ bedges, const int* __restrict__ row_ptr,
    uint2* __restrict__ edges, int n2)
{
    __shared__ int cur[BROWS];
    const int b  = blockIdx.x;
    const int t  = threadIdx.x;
    const int r0 = b * BROWS;
    if (t < BROWS) cur[t] = row_ptr[r0 + t];
    __syncthreads();
    const int s = row_ptr[r0];
    const int e = row_ptr[min(r0 + BROWS, n2)];
    for (int i = s + t; i < e; i += 128) {
        uint2 ev = bedges[i];
        int r = ev.x >> 17;
        int slot = atomicAdd(&cur[r], 1);
        edges[slot] = make_uint2(ev.x & 0x1FFFFu, ev.y);
    }
}

// ---------------- fp32 -> bf16 tables (user + item in one launch) ----------------
__global__ __launch_bounds__(256) void f32_to_bf16_2(
    const float* __restrict__ inA, ushort* __restrict__ outA, int n8A,
    const float* __restrict__ inB, ushort* __restrict__ outB, int n8B)
{
    int i = blockIdx.x * 256 + threadIdx.x;
    const float* in; ushort* out;
    if (i < n8A) { in = inA; out = outA; }
    else if (i < n8A + n8B) { i -= n8A; in = inB; out = outB; }
    else return;
    const float4* p = reinterpret_cast<const float4*>(in) + (size_t)i * 2;
    float4 A = p[0], B = p[1];
    uint4 r;
    r.x = bf16rn(A.x) | (bf16rn(A.y) << 16);
    r.y = bf16rn(A.z) | (bf16rn(A.w) << 16);
    r.z = bf16rn(B.x) | (bf16rn(B.y) << 16);
    r.w = bf16rn(B.z) | (bf16rn(B.w) << 16);
    reinterpret_cast<uint4*>(out)[i] = r;
}

// ---------------- SpMM (CSR row-gather, bf16 source, fp32 accumulate) ----------------
template <bool ADD>
__global__ __launch_bounds__(256) void spmm_bf16(
    const int* __restrict__ row_ptr, const uint2* __restrict__ edges,
    const ushort* __restrict__ xb,   // bf16 [nx,64]
    float* __restrict__ out, int nrows)
{
    int g    = (blockIdx.x * 256 + threadIdx.x) >> 4;
    int lane = threadIdx.x & 15;
    if (g >= nrows) return;
    int s = row_ptr[g], e = row_ptr[g + 1];
    float4 acc = make_float4(0.f, 0.f, 0.f, 0.f);
    int i = s;
    for (; i + 1 < e; i += 2) {
        uint2 e0 = edges[i], e1 = edges[i + 1];
        uint2 x0 = *reinterpret_cast<const uint2*>(xb + ((size_t)e0.x << 6) + lane * 4);
        uint2 x1 = *reinterpret_cast<const uint2*>(xb + ((size_t)e1.x << 6) + lane * 4);
        float v0 = __uint_as_float(e0.y);
        float v1 = __uint_as_float(e1.y);
        acc.x += v0 * __uint_as_float(x0.x << 16);
        acc.y += v0 * __uint_as_float(x0.x & 0xffff0000u);
        acc.z += v0 * __uint_as_float(x0.y << 16);
        acc.w += v0 * __uint_as_float(x0.y & 0xffff0000u);
        acc.x += v1 * __uint_as_float(x1.x << 16);
        acc.y += v1 * __uint_as_float(x1.x & 0xffff0000u);
        acc.z += v1 * __uint_as_float(x1.y << 16);
        acc.w += v1 * __uint_as_float(x1.y & 0xffff0000u);
    }
    if (i < e) {
        uint2 e0 = edges[i];
        uint2 x0 = *reinterpret_cast<const uint2*>(xb + ((size_t)e0.x << 6) + lane * 4);
        float v0 = __uint_as_float(e0.y);
        acc.x += v0 * __uint_as_float(x0.x << 16);
        acc.y += v0 * __uint_as_float(x0.x & 0xffff0000u);
        acc.z += v0 * __uint_as_float(x0.y << 16);
        acc.w += v0 * __uint_as_float(x0.y & 0xffff0000u);
    }
    float* o = out + ((size_t)g << 6) + lane * 4;
    if (ADD) {
        float4 cur = *reinterpret_cast<const float4*>(o);
        acc.x += cur.x; acc.y += cur.y; acc.z += cur.z; acc.w += cur.w;
    }
    *reinterpret_cast<float4*>(o) = acc;
}

// ---------------- register-tiled concat GEMM ----------------
__global__ __launch_bounds__(256) void gemm2(
    const float* __restrict__ a,     // new_u (spmm result) [U,64]
    const float* __restrict__ b,     // u (prev embedding)  [U,64]
    const float* __restrict__ w,     // [128,64] row-major
    float* __restrict__ outf,        // fp32 out [U,64]
    ushort* __restrict__ outb,       // bf16 out [U,64] or nullptr
    int U)
{
    __shared__ float sIn[64 * 128];
    __shared__ float sWt[64 * 128];
    const int t    = threadIdx.x;
    const int base = blockIdx.x * 64;

    // stage W^T, XOR-swizzled: dw(col,j) = col*128 + ((((j>>2)^((col>>1)&7))<<2) | (j&3))
    for (int i = t; i < 2048; i += 256) {
        int j  = i >> 4;
        int c4 = (i & 15) << 2;
        float4 wv = reinterpret_cast<const float4*>(w)[i];
        float vv[4] = { wv.x, wv.y, wv.z, wv.w };
        #pragma unroll
        for (int e2 = 0; e2 < 4; ++e2) {
            int col = c4 + e2;
            int dw  = col * 128 + ((((j >> 2) ^ ((col >> 1) & 7)) << 2) | (j & 3));
            sWt[dw] = vv[e2];
        }
    }
    // stage inputs: sIn[row][0..63] = a-row, [64..127] = b-row
    for (int i = t; i < 2048; i += 256) {
        int row  = i >> 5;
        int q    = i & 31;
        int grow = base + row;
        float4 v = make_float4(0.f, 0.f, 0.f, 0.f);
        int qq = q & 15;
        if (grow < U) {
            const float* src = (q < 16) ? a : b;
            v = *reinterpret_cast<const float4*>(src + ((size_t)grow << 6) + qq * 4);
        }
        int off = (q < 16) ? qq * 4 : 64 + qq * 4;
        *reinterpret_cast<float4*>(&sIn[row * 128 + off]) = v;
    }
    __syncthreads();

    const int w_ = t >> 6;
    const int l  = t & 63;
    const int h  = l >> 5;
    const int lq = l & 31;
    const int c0 = lq * 2;
    const int rb = w_ * 16 + h * 8;
    const int sw = lq & 7;

    float acc[8][2];
    #pragma unroll
    for (int r = 0; r < 8; ++r) { acc[r][0] = 0.f; acc[r][1] = 0.f; }

    #pragma unroll 4
    for (int j4 = 0; j4 < 32; ++j4) {
        int so = ((j4 ^ sw) << 2);
        float4 w40 = *reinterpret_cast<const float4*>(&sWt[c0 * 128 + so]);
        float4 w41 = *reinterpret_cast<const float4*>(&sWt[(c0 + 1) * 128 + so]);
        #pragma unroll
        for (int r = 0; r < 8; ++r) {
            float4 iv = *reinterpret_cast<const float4*>(&sIn[(rb + r) * 128 + j4 * 4]);
            acc[r][0] += iv.x * w40.x + iv.y * w40.y + iv.z * w40.z + iv.w * w40.w;
            acc[r][1] += iv.x * w41.x + iv.y * w41.y + iv.z * w41.z + iv.w * w41.w;
        }
    }

    #pragma unroll
    for (int r = 0; r < 8; ++r) {
        int grow = base + rb + r;
        if (grow < U) {
            *reinterpret_cast<float2*>(&outf[((size_t)grow << 6) + c0]) =
                make_float2(acc[r][0], acc[r][1]);
            if (outb) {
                unsigned pk = bf16rn(acc[r][0]) | (bf16rn(acc[r][1]) << 16);
                *reinterpret_cast<unsigned*>(outb + ((size_t)grow << 6) + c0) = pk;
            }
        }
    }
}

extern "C" void kernel_launch(void* const* d_in, const int* in_sizes, int n_in,
                              void* d_out, int out_size, void* d_ws, size_t ws_size,
                              hipStream_t stream)
{
    const float* user_emb    = (const float*)d_in[0];
    const float* item_emb    = (const float*)d_in[1];
    const float* weights     = (const float*)d_in[2];
    const float* social_vals = (const float*)d_in[3];
    const float* inter_vals  = (const float*)d_in[4];
    const int*   social_rows = (const int*)d_in[5];
    const int*   social_cols = (const int*)d_in[6];
    const int*   inter_rows  = (const int*)d_in[7];
    const int*   inter_cols  = (const int*)d_in[8];

    const int D  = DD;
    const int U  = in_sizes[0] / D;
    const int I  = in_sizes[1] / D;
    const int L  = in_sizes[2] / (2 * D * D);
    const int ES = in_sizes[3];
    const int EI = in_sizes[4];

    float* out      = (float*)d_out;           // final_u [U, D]
    float* out_item = out + (size_t)U * D;     // item_emb passthrough [I, D]

    // ---- workspace layout ----
    char* p = (char*)d_ws;
    size_t off = 0;
    auto take = [&](size_t bytes) { char* r = p + off; off += align16(bytes); return r; };

    const int n2   = 2 * U;
    const int NB   = (n2 + BROWS - 1) / BROWS;
    const int Etot = ES + EI;

    int*    row_ptr = (int*)take((size_t)(n2 + 1) * sizeof(int));
    int*    counts  = (int*)take((size_t)n2 * sizeof(int));
    int*    bcur    = (int*)take((size_t)NB * sizeof(int));
    int*    bsums   = (int*)take(1024 * sizeof(int));
    uint2*  edges   = (uint2*)take((size_t)Etot * sizeof(uint2));
    ushort* ubf     = (ushort*)take((size_t)U * D * sizeof(ushort));
    ushort* ibf     = (ushort*)take((size_t)I * D * sizeof(ushort));
    float*  tmpA    = (float*)take((size_t)U * D * sizeof(float));
    float*  uB      = (float*)take((size_t)U * D * sizeof(float));

    // bedges aliases tmpA: fully consumed by bucket_fin before the first spmm writes tmpA
    uint2* bedges = (uint2*)tmpA;

    // ---- CSR build: row hist -> scan (row_ptr + bucket cursors) -> bucket scatter -> finalize ----
    hipMemsetAsync(counts, 0, (size_t)n2 * sizeof(int), stream);
    hist_rows<<<(Etot + 255) / 256, 256, 0, stream>>>(social_rows, inter_rows, counts, ES, EI, U);
    const int nb = (n2 + 2047) / 2048;
    scan_partial<<<nb, 256, 0, stream>>>(counts, row_ptr, bsums, n2);
    scan_top<<<1, 1, 0, stream>>>(bsums, nb, row_ptr, n2);
    scan_add_bcur<<<(n2 + 255) / 256, 256, 0, stream>>>(row_ptr, bcur, bsums, n2);
    phaseA<<<(Etot + 255) / 256, 256, 0, stream>>>(
        social_rows, social_cols, social_vals,
        inter_rows, inter_cols, inter_vals,
        bcur, bedges, ES, EI, U);
    bucket_fin<<<NB, 128, 0, stream>>>(bedges, row_ptr, edges, n2);

    // ---- bf16 gather tables ----
    const int u8 = U * D / 8, i8 = I * D / 8;
    f32_to_bf16_2<<<(u8 + i8 + 255) / 256, 256, 0, stream>>>(
        user_emb, ubf, u8, item_emb, ibf, i8);

    // ---- layers ----
    const int spmm_grid = ((U * 16) + 255) / 256;
    const int gemm_grid = (U + 63) / 64;
    const float* uprev = user_emb;
    for (int k = 0; k < L; ++k) {
        const float* wk = weights + (size_t)k * 2 * D * D;
        spmm_bf16<false><<<spmm_grid, 256, 0, stream>>>(row_ptr, edges, ubf, tmpA, U);
        if (k == L - 1) {
            gemm2<<<gemm_grid, 256, 0, stream>>>(tmpA, uprev, wk, out, (ushort*)nullptr, U);
        } else {
            gemm2<<<gemm_grid, 256, 0, stream>>>(tmpA, uprev, wk, uB, ubf, U);
            uprev = uB;
        }
    }

    // final_u += A_inter @ item_emb (bf16 gather, fp32 accumulate into d_out)
    spmm_bf16<true><<<spmm_grid, 256, 0, stream>>>(row_ptr + U, edges, ibf, out, U);

    // output 1: item_emb passthrough
    hipMemcpyAsync(out_item, item_emb, (size_t)I * D * sizeof(float),
                   hipMemcpyDeviceToDevice, stream);
}

// Round 7
// 321.556 us; speedup vs baseline: 5.1025x; 1.4898x over previous
//
#include <hip/hip_runtime.h>

#define DD 64        // embedding dim
#define RPCB 1024    // rows per coarse bucket
#define CBSH 10      // log2(RPCB)
#define EPB 8192     // edges per partition block

static inline size_t align16(size_t x) { return (x + 15) & ~(size_t)15; }

__device__ __forceinline__ unsigned bf16rn(float f) {
    unsigned u = __float_as_uint(f);
    return (u + 0x7fffu + ((u >> 16) & 1u)) >> 16;   // RNE
}

// ---------------- P1: per-block histogram over coarse buckets ----------------
__global__ __launch_bounds__(256) void p1_hist(
    const int* __restrict__ srows, const int* __restrict__ irows,
    int* __restrict__ hmat, int ES, int EI, int U, int CB, int NBLK)
{
    __shared__ int hist[256];          // CB <= 256 (U <= 131072)
    const int b = blockIdx.x, t = threadIdx.x;
    for (int i = t; i < CB; i += 256) hist[i] = 0;
    __syncthreads();
    const int e1 = min(b * EPB + EPB, ES + EI);
    for (int e = b * EPB + t; e < e1; e += 256) {
        int row = (e < ES) ? srows[e] : U + irows[e - ES];
        atomicAdd(&hist[row >> CBSH], 1);
    }
    __syncthreads();
    for (int i = t; i < CB; i += 256) hmat[(size_t)i * NBLK + b] = hist[i];
}

// ---------------- scan helpers ----------------
__global__ __launch_bounds__(256) void scan_partial(
    const int* __restrict__ in, int* __restrict__ out, int* __restrict__ bsums, int n)
{
    __shared__ int sh[256];
    int base = blockIdx.x * 2048 + threadIdx.x * 8;
    int v[8];
    int tsum = 0;
    #pragma unroll
    for (int j = 0; j < 8; ++j) {
        int idx = base + j;
        int x = (idx < n) ? in[idx] : 0;
        v[j] = tsum;
        tsum += x;
    }
    sh[threadIdx.x] = tsum;
    __syncthreads();
    for (int off = 1; off < 256; off <<= 1) {
        int t = (threadIdx.x >= off) ? sh[threadIdx.x - off] : 0;
        __syncthreads();
        sh[threadIdx.x] += t;
        __syncthreads();
    }
    int texc = sh[threadIdx.x] - tsum;
    #pragma unroll
    for (int j = 0; j < 8; ++j) {
        int idx = base + j;
        if (idx < n) out[idx] = texc + v[j];
    }
    if (threadIdx.x == 255) bsums[blockIdx.x] = sh[255];
}

__global__ void scan_top(int* bsums, int nb)
{
    int run = 0;
    for (int i = 0; i < nb; ++i) { int t = bsums[i]; bsums[i] = run; run += t; }
}

__global__ __launch_bounds__(256) void scan_add(
    int* __restrict__ out, const int* __restrict__ bsums, int n)
{
    int i = blockIdx.x * 256 + threadIdx.x;
    if (i < n) out[i] += bsums[i >> 11];
}

// ---------------- P2: partition scatter into per-(bucket,block) exclusive ranges ----------------
// payload: .x = (row_lo << 17) | col  (row_lo 10b, col <= 17b), .y = fp32 val bits
__global__ __launch_bounds__(256) void p2_scatter(
    const int* __restrict__ srows, const int* __restrict__ scols, const float* __restrict__ svals,
    const int* __restrict__ irows, const int* __restrict__ icols, const float* __restrict__ ivals,
    const int* __restrict__ hS, uint2* __restrict__ bedges,
    int ES, int EI, int U, int CB, int NBLK)
{
    __shared__ int cur[256];
    const int b = blockIdx.x, t = threadIdx.x;
    for (int i = t; i < CB; i += 256) cur[i] = hS[(size_t)i * NBLK + b];
    __syncthreads();
    const int e1 = min(b * EPB + EPB, ES + EI);
    for (int e = b * EPB + t; e < e1; e += 256) {
        int row, col; unsigned val;
        if (e < ES) { row = srows[e]; col = scols[e]; val = __float_as_uint(svals[e]); }
        else {
            int i = e - ES;
            row = U + irows[i]; col = icols[i]; val = __float_as_uint(ivals[i]);
        }
        int slot = atomicAdd(&cur[row >> CBSH], 1);
        bedges[slot] = make_uint2(((unsigned)(row & (RPCB - 1)) << 17) | (unsigned)col, val);
    }
}

// ---------------- P3: per-bucket finalize -> row_ptr + exact CSR slots ----------------
__global__ __launch_bounds__(256) void p3_fin(
    const uint2* __restrict__ bedges, const int* __restrict__ hS,
    int* __restrict__ row_ptr, uint2* __restrict__ edges,
    int n2, int Etot, int CB, int NBLK)
{
    __shared__ int cnt[RPCB];
    __shared__ int sh[256];
    const int cb = blockIdx.x, t = threadIdx.x;
    const int r0 = cb << CBSH;
    const int s = hS[(size_t)cb * NBLK];
    const int e = (cb == CB - 1) ? Etot : hS[(size_t)(cb + 1) * NBLK];

    #pragma unroll
    for (int j = 0; j < RPCB / 256; ++j) cnt[t + j * 256] = 0;
    __syncthreads();
    for (int i = s + t; i < e; i += 256) atomicAdd(&cnt[bedges[i].x >> 17], 1);
    __syncthreads();

    // exclusive scan of cnt[RPCB]: 4 consecutive per thread + block scan
    int c[4]; int tot = 0;
    #pragma unroll
    for (int j = 0; j < 4; ++j) { int x = cnt[t * 4 + j]; c[j] = tot; tot += x; }
    sh[t] = tot;
    __syncthreads();
    for (int off = 1; off < 256; off <<= 1) {
        int v = (t >= off) ? sh[t - off] : 0;
        __syncthreads();
        sh[t] += v;
        __syncthreads();
    }
    int excl = sh[t] - tot;
    #pragma unroll
    for (int j = 0; j < 4; ++j) {
        int r = t * 4 + j;
        int v = s + excl + c[j];
        cnt[r] = v;                         // becomes cursor
        int gr = r0 + r;
        if (gr < n2) row_ptr[gr] = v;
    }
    if (cb == CB - 1 && t == 0) row_ptr[n2] = Etot;
    __syncthreads();

    for (int i = s + t; i < e; i += 256) {
        uint2 ev = bedges[i];
        int r = ev.x >> 17;
        int slot = atomicAdd(&cnt[r], 1);
        edges[slot] = make_uint2(ev.x & 0x1FFFFu, ev.y);
    }
}

// ---------------- fp32 -> bf16 tables (user + item in one launch) ----------------
__global__ __launch_bounds__(256) void f32_to_bf16_2(
    const float* __restrict__ inA, ushort* __restrict__ outA, int n8A,
    const float* __restrict__ inB, ushort* __restrict__ outB, int n8B)
{
    int i = blockIdx.x * 256 + threadIdx.x;
    const float* in; ushort* out;
    if (i < n8A) { in = inA; out = outA; }
    else if (i < n8A + n8B) { i -= n8A; in = inB; out = outB; }
    else return;
    const float4* p = reinterpret_cast<const float4*>(in) + (size_t)i * 2;
    float4 A = p[0], B = p[1];
    uint4 r;
    r.x = bf16rn(A.x) | (bf16rn(A.y) << 16);
    r.y = bf16rn(A.z) | (bf16rn(A.w) << 16);
    r.z = bf16rn(B.x) | (bf16rn(B.y) << 16);
    r.w = bf16rn(B.z) | (bf16rn(B.w) << 16);
    reinterpret_cast<uint4*>(out)[i] = r;
}

// ---------------- SpMM (CSR row-gather, bf16 source, fp32 accumulate) ----------------
template <bool ADD>
__global__ __launch_bounds__(256) void spmm_bf16(
    const int* __restrict__ row_ptr, const uint2* __restrict__ edges,
    const ushort* __restrict__ xb,   // bf16 [nx,64]
    float* __restrict__ out, int nrows)
{
    int g    = (blockIdx.x * 256 + threadIdx.x) >> 4;
    int lane = threadIdx.x & 15;
    if (g >= nrows) return;
    int s = row_ptr[g], e = row_ptr[g + 1];
    float4 acc = make_float4(0.f, 0.f, 0.f, 0.f);
    int i = s;
    for (; i + 1 < e; i += 2) {
        uint2 e0 = edges[i], e1 = edges[i + 1];
        uint2 x0 = *reinterpret_cast<const uint2*>(xb + ((size_t)e0.x << 6) + lane * 4);
        uint2 x1 = *reinterpret_cast<const uint2*>(xb + ((size_t)e1.x << 6) + lane * 4);
        float v0 = __uint_as_float(e0.y);
        float v1 = __uint_as_float(e1.y);
        acc.x += v0 * __uint_as_float(x0.x << 16);
        acc.y += v0 * __uint_as_float(x0.x & 0xffff0000u);
        acc.z += v0 * __uint_as_float(x0.y << 16);
        acc.w += v0 * __uint_as_float(x0.y & 0xffff0000u);
        acc.x += v1 * __uint_as_float(x1.x << 16);
        acc.y += v1 * __uint_as_float(x1.x & 0xffff0000u);
        acc.z += v1 * __uint_as_float(x1.y << 16);
        acc.w += v1 * __uint_as_float(x1.y & 0xffff0000u);
    }
    if (i < e) {
        uint2 e0 = edges[i];
        uint2 x0 = *reinterpret_cast<const uint2*>(xb + ((size_t)e0.x << 6) + lane * 4);
        float v0 = __uint_as_float(e0.y);
        acc.x += v0 * __uint_as_float(x0.x << 16);
        acc.y += v0 * __uint_as_float(x0.x & 0xffff0000u);
        acc.z += v0 * __uint_as_float(x0.y << 16);
        acc.w += v0 * __uint_as_float(x0.y & 0xffff0000u);
    }
    float* o = out + ((size_t)g << 6) + lane * 4;
    if (ADD) {
        float4 cur = *reinterpret_cast<const float4*>(o);
        acc.x += cur.x; acc.y += cur.y; acc.z += cur.z; acc.w += cur.w;
    }
    *reinterpret_cast<float4*>(o) = acc;
}

// ---------------- register-tiled concat GEMM ----------------
__global__ __launch_bounds__(256) void gemm2(
    const float* __restrict__ a,     // new_u (spmm result) [U,64]
    const float* __restrict__ b,     // u (prev embedding)  [U,64]
    const float* __restrict__ w,     // [128,64] row-major
    float* __restrict__ outf,        // fp32 out [U,64]
    ushort* __restrict__ outb,       // bf16 out [U,64] or nullptr
    int U)
{
    __shared__ float sIn[64 * 128];
    __shared__ float sWt[64 * 128];
    const int t    = threadIdx.x;
    const int base = blockIdx.x * 64;

    for (int i = t; i < 2048; i += 256) {
        int j  = i >> 4;
        int c4 = (i & 15) << 2;
        float4 wv = reinterpret_cast<const float4*>(w)[i];
        float vv[4] = { wv.x, wv.y, wv.z, wv.w };
        #pragma unroll
        for (int e2 = 0; e2 < 4; ++e2) {
            int col = c4 + e2;
            int dw  = col * 128 + ((((j >> 2) ^ ((col >> 1) & 7)) << 2) | (j & 3));
            sWt[dw] = vv[e2];
        }
    }
    for (int i = t; i < 2048; i += 256) {
        int row  = i >> 5;
        int q    = i & 31;
        int grow = base + row;
        float4 v = make_float4(0.f, 0.f, 0.f, 0.f);
        int qq = q & 15;
        if (grow < U) {
            const float* src = (q < 16) ? a : b;
            v = *reinterpret_cast<const float4*>(src + ((size_t)grow << 6) + qq * 4);
        }
        int off = (q < 16) ? qq * 4 : 64 + qq * 4;
        *reinterpret_cast<float4*>(&sIn[row * 128 + off]) = v;
    }
    __syncthreads();

    const int w_ = t >> 6;
    const int l  = t & 63;
    const int h  = l >> 5;
    const int lq = l & 31;
    const int c0 = lq * 2;
    const int rb = w_ * 16 + h * 8;
    const int sw = lq & 7;

    float acc[8][2];
    #pragma unroll
    for (int r = 0; r < 8; ++r) { acc[r][0] = 0.f; acc[r][1] = 0.f; }

    #pragma unroll 4
    for (int j4 = 0; j4 < 32; ++j4) {
        int so = ((j4 ^ sw) << 2);
        float4 w40 = *reinterpret_cast<const float4*>(&sWt[c0 * 128 + so]);
        float4 w41 = *reinterpret_cast<const float4*>(&sWt[(c0 + 1) * 128 + so]);
        #pragma unroll
        for (int r = 0; r < 8; ++r) {
            float4 iv = *reinterpret_cast<const float4*>(&sIn[(rb + r) * 128 + j4 * 4]);
            acc[r][0] += iv.x * w40.x + iv.y * w40.y + iv.z * w40.z + iv.w * w40.w;
            acc[r][1] += iv.x * w41.x + iv.y * w41.y + iv.z * w41.z + iv.w * w41.w;
        }
    }

    #pragma unroll
    for (int r = 0; r < 8; ++r) {
        int grow = base + rb + r;
        if (grow < U) {
            *reinterpret_cast<float2*>(&outf[((size_t)grow << 6) + c0]) =
                make_float2(acc[r][0], acc[r][1]);
            if (outb) {
                unsigned pk = bf16rn(acc[r][0]) | (bf16rn(acc[r][1]) << 16);
                *reinterpret_cast<unsigned*>(outb + ((size_t)grow << 6) + c0) = pk;
            }
        }
    }
}

extern "C" void kernel_launch(void* const* d_in, const int* in_sizes, int n_in,
                              void* d_out, int out_size, void* d_ws, size_t ws_size,
                              hipStream_t stream)
{
    const float* user_emb    = (const float*)d_in[0];
    const float* item_emb    = (const float*)d_in[1];
    const float* weights     = (const float*)d_in[2];
    const float* social_vals = (const float*)d_in[3];
    const float* inter_vals  = (const float*)d_in[4];
    const int*   social_rows = (const int*)d_in[5];
    const int*   social_cols = (const int*)d_in[6];
    const int*   inter_rows  = (const int*)d_in[7];
    const int*   inter_cols  = (const int*)d_in[8];

    const int D  = DD;
    const int U  = in_sizes[0] / D;
    const int I  = in_sizes[1] / D;
    const int L  = in_sizes[2] / (2 * D * D);
    const int ES = in_sizes[3];
    const int EI = in_sizes[4];

    float* out      = (float*)d_out;           // final_u [U, D]
    float* out_item = out + (size_t)U * D;     // item_emb passthrough [I, D]

    // ---- workspace layout ----
    char* p = (char*)d_ws;
    size_t off = 0;
    auto take = [&](size_t bytes) { char* r = p + off; off += align16(bytes); return r; };

    const int n2   = 2 * U;
    const int CB   = (n2 + RPCB - 1) >> CBSH;       // coarse buckets (<= 256)
    const int Etot = ES + EI;
    const int NBLK = (Etot + EPB - 1) / EPB;
    const int NH   = CB * NBLK;

    int*    row_ptr = (int*)take((size_t)(n2 + 1) * sizeof(int));
    int*    hmat    = (int*)take((size_t)NH * sizeof(int));
    int*    hS      = (int*)take((size_t)NH * sizeof(int));
    int*    bsums   = (int*)take(1024 * sizeof(int));
    uint2*  edges   = (uint2*)take((size_t)Etot * sizeof(uint2));
    ushort* ubf     = (ushort*)take((size_t)U * D * sizeof(ushort));
    ushort* ibf     = (ushort*)take((size_t)I * D * sizeof(ushort));
    float*  tmpA    = (float*)take((size_t)U * D * sizeof(float));
    float*  uB      = (float*)take((size_t)U * D * sizeof(float));

    // bedges aliases tmpA: fully consumed by p3_fin before the first spmm writes tmpA
    uint2* bedges = (uint2*)tmpA;

    // ---- CSR build: partition histogram -> scan -> partition scatter -> bucket finalize ----
    p1_hist<<<NBLK, 256, 0, stream>>>(social_rows, inter_rows, hmat, ES, EI, U, CB, NBLK);
    const int nb = (NH + 2047) / 2048;
    scan_partial<<<nb, 256, 0, stream>>>(hmat, hS, bsums, NH);
    scan_top<<<1, 1, 0, stream>>>(bsums, nb);
    scan_add<<<(NH + 255) / 256, 256, 0, stream>>>(hS, bsums, NH);
    p2_scatter<<<NBLK, 256, 0, stream>>>(
        social_rows, social_cols, social_vals,
        inter_rows, inter_cols, inter_vals,
        hS, bedges, ES, EI, U, CB, NBLK);
    p3_fin<<<CB, 256, 0, stream>>>(bedges, hS, row_ptr, edges, n2, Etot, CB, NBLK);

    // ---- bf16 gather tables ----
    const int u8 = U * D / 8, i8 = I * D / 8;
    f32_to_bf16_2<<<(u8 + i8 + 255) / 256, 256, 0, stream>>>(
        user_emb, ubf, u8, item_emb, ibf, i8);

    // ---- layers ----
    const int spmm_grid = ((U * 16) + 255) / 256;
    const int gemm_grid = (U + 63) / 64;
    const float* uprev = user_emb;
    for (int k = 0; k < L; ++k) {
        const float* wk = weights + (size_t)k * 2 * D * D;
        spmm_bf16<false><<<spmm_grid, 256, 0, stream>>>(row_ptr, edges, ubf, tmpA, U);
        if (k == L - 1) {
            gemm2<<<gemm_grid, 256, 0, stream>>>(tmpA, uprev, wk, out, (ushort*)nullptr, U);
        } else {
            gemm2<<<gemm_grid, 256, 0, stream>>>(tmpA, uprev, wk, uB, ubf, U);
            uprev = uB;
        }
    }

    // final_u += A_inter @ item_emb (bf16 gather, fp32 accumulate into d_out)
    spmm_bf16<true><<<spmm_grid, 256, 0, stream>>>(row_ptr + U, edges, ibf, out, U);

    // output 1: item_emb passthrough
    hipMemcpyAsync(out_item, item_emb, (size_t)I * D * sizeof(float),
                   hipMemcpyDeviceToDevice, stream);
}

// Round 8
// 248.238 us; speedup vs baseline: 6.6095x; 1.2954x over previous
//
#include <hip/hip_runtime.h>

#define DD 64        // embedding dim
#define RPCB 1024    // rows per coarse bucket
#define CBSH 10      // log2(RPCB)
#define EPB 8192     // edges per partition block

static inline size_t align16(size_t x) { return (x + 15) & ~(size_t)15; }

__device__ __forceinline__ unsigned bf16rn(float f) {
    unsigned u = __float_as_uint(f);
    return (u + 0x7fffu + ((u >> 16) & 1u)) >> 16;   // RNE
}

typedef __attribute__((ext_vector_type(8))) short bf16x8;  // 8 bf16 (4 VGPRs)
typedef __attribute__((ext_vector_type(4))) float f32x4;   // 4 fp32 acc

// ---------------- P1: per-block histogram over coarse buckets ----------------
__global__ __launch_bounds__(256) void p1_hist(
    const int* __restrict__ srows, const int* __restrict__ irows,
    int* __restrict__ hmat, int ES, int EI, int U, int CB, int NBLK)
{
    __shared__ int hist[256];          // CB <= 256 (U <= 131072)
    const int b = blockIdx.x, t = threadIdx.x;
    for (int i = t; i < CB; i += 256) hist[i] = 0;
    __syncthreads();
    const int e1 = min(b * EPB + EPB, ES + EI);
    for (int e = b * EPB + t; e < e1; e += 256) {
        int row = (e < ES) ? srows[e] : U + irows[e - ES];
        atomicAdd(&hist[row >> CBSH], 1);
    }
    __syncthreads();
    for (int i = t; i < CB; i += 256) hmat[(size_t)i * NBLK + b] = hist[i];
}

// ---------------- scan helpers ----------------
__global__ __launch_bounds__(256) void scan_partial(
    const int* __restrict__ in, int* __restrict__ out, int* __restrict__ bsums, int n)
{
    __shared__ int sh[256];
    int base = blockIdx.x * 2048 + threadIdx.x * 8;
    int v[8];
    int tsum = 0;
    #pragma unroll
    for (int j = 0; j < 8; ++j) {
        int idx = base + j;
        int x = (idx < n) ? in[idx] : 0;
        v[j] = tsum;
        tsum += x;
    }
    sh[threadIdx.x] = tsum;
    __syncthreads();
    for (int off = 1; off < 256; off <<= 1) {
        int t = (threadIdx.x >= off) ? sh[threadIdx.x - off] : 0;
        __syncthreads();
        sh[threadIdx.x] += t;
        __syncthreads();
    }
    int texc = sh[threadIdx.x] - tsum;
    #pragma unroll
    for (int j = 0; j < 8; ++j) {
        int idx = base + j;
        if (idx < n) out[idx] = texc + v[j];
    }
    if (threadIdx.x == 255) bsums[blockIdx.x] = sh[255];
}

__global__ void scan_top(int* bsums, int nb)
{
    int run = 0;
    for (int i = 0; i < nb; ++i) { int t = bsums[i]; bsums[i] = run; run += t; }
}

__global__ __launch_bounds__(256) void scan_add(
    int* __restrict__ out, const int* __restrict__ bsums, int n)
{
    int i = blockIdx.x * 256 + threadIdx.x;
    if (i < n) out[i] += bsums[i >> 11];
}

// ---------------- P2: partition scatter into per-(bucket,block) exclusive ranges ----------------
__global__ __launch_bounds__(256) void p2_scatter(
    const int* __restrict__ srows, const int* __restrict__ scols, const float* __restrict__ svals,
    const int* __restrict__ irows, const int* __restrict__ icols, const float* __restrict__ ivals,
    const int* __restrict__ hS, uint2* __restrict__ bedges,
    int ES, int EI, int U, int CB, int NBLK)
{
    __shared__ int cur[256];
    const int b = blockIdx.x, t = threadIdx.x;
    for (int i = t; i < CB; i += 256) cur[i] = hS[(size_t)i * NBLK + b];
    __syncthreads();
    const int e1 = min(b * EPB + EPB, ES + EI);
    for (int e = b * EPB + t; e < e1; e += 256) {
        int row, col; unsigned val;
        if (e < ES) { row = srows[e]; col = scols[e]; val = __float_as_uint(svals[e]); }
        else {
            int i = e - ES;
            row = U + irows[i]; col = icols[i]; val = __float_as_uint(ivals[i]);
        }
        int slot = atomicAdd(&cur[row >> CBSH], 1);
        bedges[slot] = make_uint2(((unsigned)(row & (RPCB - 1)) << 17) | (unsigned)col, val);
    }
}

// ---------------- P3: per-bucket finalize -> row_ptr + exact CSR slots ----------------
__global__ __launch_bounds__(256) void p3_fin(
    const uint2* __restrict__ bedges, const int* __restrict__ hS,
    int* __restrict__ row_ptr, uint2* __restrict__ edges,
    int n2, int Etot, int CB, int NBLK)
{
    __shared__ int cnt[RPCB];
    __shared__ int sh[256];
    const int cb = blockIdx.x, t = threadIdx.x;
    const int r0 = cb << CBSH;
    const int s = hS[(size_t)cb * NBLK];
    const int e = (cb == CB - 1) ? Etot : hS[(size_t)(cb + 1) * NBLK];

    #pragma unroll
    for (int j = 0; j < RPCB / 256; ++j) cnt[t + j * 256] = 0;
    __syncthreads();
    for (int i = s + t; i < e; i += 256) atomicAdd(&cnt[bedges[i].x >> 17], 1);
    __syncthreads();

    int c[4]; int tot = 0;
    #pragma unroll
    for (int j = 0; j < 4; ++j) { int x = cnt[t * 4 + j]; c[j] = tot; tot += x; }
    sh[t] = tot;
    __syncthreads();
    for (int off = 1; off < 256; off <<= 1) {
        int v = (t >= off) ? sh[t - off] : 0;
        __syncthreads();
        sh[t] += v;
        __syncthreads();
    }
    int excl = sh[t] - tot;
    #pragma unroll
    for (int j = 0; j < 4; ++j) {
        int r = t * 4 + j;
        int v = s + excl + c[j];
        cnt[r] = v;                         // becomes cursor
        int gr = r0 + r;
        if (gr < n2) row_ptr[gr] = v;
    }
    if (cb == CB - 1 && t == 0) row_ptr[n2] = Etot;
    __syncthreads();

    for (int i = s + t; i < e; i += 256) {
        uint2 ev = bedges[i];
        int r = ev.x >> 17;
        int slot = atomicAdd(&cnt[r], 1);
        edges[slot] = make_uint2(ev.x & 0x1FFFFu, ev.y);
    }
}

// ---------------- fp32 -> bf16 tables (user + item in one launch) ----------------
__global__ __launch_bounds__(256) void f32_to_bf16_2(
    const float* __restrict__ inA, ushort* __restrict__ outA, int n8A,
    const float* __restrict__ inB, ushort* __restrict__ outB, int n8B)
{
    int i = blockIdx.x * 256 + threadIdx.x;
    const float* in; ushort* out;
    if (i < n8A) { in = inA; out = outA; }
    else if (i < n8A + n8B) { i -= n8A; in = inB; out = outB; }
    else return;
    const float4* p = reinterpret_cast<const float4*>(in) + (size_t)i * 2;
    float4 A = p[0], B = p[1];
    uint4 r;
    r.x = bf16rn(A.x) | (bf16rn(A.y) << 16);
    r.y = bf16rn(A.z) | (bf16rn(A.w) << 16);
    r.z = bf16rn(B.x) | (bf16rn(B.y) << 16);
    r.w = bf16rn(B.z) | (bf16rn(B.w) << 16);
    reinterpret_cast<uint4*>(out)[i] = r;
}

// ---------------- weights: fp32 [L][128][64] -> bf16 W^T [L][64][128] ----------------
__global__ __launch_bounds__(256) void conv_w(
    const float* __restrict__ w, ushort* __restrict__ wtb, int n)  // n = L*8192
{
    int idx = blockIdx.x * 256 + threadIdx.x;
    if (idx >= n) return;
    int l = idx >> 13;
    int r = idx & 8191;
    int c = r >> 7;          // col 0..63
    int k = r & 127;         // k   0..127
    wtb[idx] = (ushort)bf16rn(w[(size_t)l * 8192 + k * 64 + c]);
}

// ---------------- SpMM -> bf16 output (CSR row-gather, fp32 accumulate) ----------------
__global__ __launch_bounds__(256) void spmm_to_bf16(
    const int* __restrict__ row_ptr, const uint2* __restrict__ edges,
    const ushort* __restrict__ xb,   // bf16 [nx,64]
    ushort* __restrict__ outb, int nrows)
{
    int g    = (blockIdx.x * 256 + threadIdx.x) >> 4;
    int lane = threadIdx.x & 15;
    if (g >= nrows) return;
    int s = row_ptr[g], e = row_ptr[g + 1];
    float4 acc = make_float4(0.f, 0.f, 0.f, 0.f);
    int i = s;
    for (; i + 1 < e; i += 2) {
        uint2 e0 = edges[i], e1 = edges[i + 1];
        uint2 x0 = *reinterpret_cast<const uint2*>(xb + ((size_t)e0.x << 6) + lane * 4);
        uint2 x1 = *reinterpret_cast<const uint2*>(xb + ((size_t)e1.x << 6) + lane * 4);
        float v0 = __uint_as_float(e0.y);
        float v1 = __uint_as_float(e1.y);
        acc.x += v0 * __uint_as_float(x0.x << 16);
        acc.y += v0 * __uint_as_float(x0.x & 0xffff0000u);
        acc.z += v0 * __uint_as_float(x0.y << 16);
        acc.w += v0 * __uint_as_float(x0.y & 0xffff0000u);
        acc.x += v1 * __uint_as_float(x1.x << 16);
        acc.y += v1 * __uint_as_float(x1.x & 0xffff0000u);
        acc.z += v1 * __uint_as_float(x1.y << 16);
        acc.w += v1 * __uint_as_float(x1.y & 0xffff0000u);
    }
    if (i < e) {
        uint2 e0 = edges[i];
        uint2 x0 = *reinterpret_cast<const uint2*>(xb + ((size_t)e0.x << 6) + lane * 4);
        float v0 = __uint_as_float(e0.y);
        acc.x += v0 * __uint_as_float(x0.x << 16);
        acc.y += v0 * __uint_as_float(x0.x & 0xffff0000u);
        acc.z += v0 * __uint_as_float(x0.y << 16);
        acc.w += v0 * __uint_as_float(x0.y & 0xffff0000u);
    }
    unsigned p0 = bf16rn(acc.x) | (bf16rn(acc.y) << 16);
    unsigned p1 = bf16rn(acc.z) | (bf16rn(acc.w) << 16);
    *reinterpret_cast<uint2*>(outb + ((size_t)g << 6) + lane * 4) = make_uint2(p0, p1);
}

// ---------------- SpMM -> fp32 accumulate-add (for the final inter pass) ----------------
__global__ __launch_bounds__(256) void spmm_add_f32(
    const int* __restrict__ row_ptr, const uint2* __restrict__ edges,
    const ushort* __restrict__ xb,   // bf16 [nx,64]
    float* __restrict__ out, int nrows)
{
    int g    = (blockIdx.x * 256 + threadIdx.x) >> 4;
    int lane = threadIdx.x & 15;
    if (g >= nrows) return;
    int s = row_ptr[g], e = row_ptr[g + 1];
    float4 acc = make_float4(0.f, 0.f, 0.f, 0.f);
    int i = s;
    for (; i + 1 < e; i += 2) {
        uint2 e0 = edges[i], e1 = edges[i + 1];
        uint2 x0 = *reinterpret_cast<const uint2*>(xb + ((size_t)e0.x << 6) + lane * 4);
        uint2 x1 = *reinterpret_cast<const uint2*>(xb + ((size_t)e1.x << 6) + lane * 4);
        float v0 = __uint_as_float(e0.y);
        float v1 = __uint_as_float(e1.y);
        acc.x += v0 * __uint_as_float(x0.x << 16);
        acc.y += v0 * __uint_as_float(x0.x & 0xffff0000u);
        acc.z += v0 * __uint_as_float(x0.y << 16);
        acc.w += v0 * __uint_as_float(x0.y & 0xffff0000u);
        acc.x += v1 * __uint_as_float(x1.x << 16);
        acc.y += v1 * __uint_as_float(x1.x & 0xffff0000u);
        acc.z += v1 * __uint_as_float(x1.y << 16);
        acc.w += v1 * __uint_as_float(x1.y & 0xffff0000u);
    }
    if (i < e) {
        uint2 e0 = edges[i];
        uint2 x0 = *reinterpret_cast<const uint2*>(xb + ((size_t)e0.x << 6) + lane * 4);
        float v0 = __uint_as_float(e0.y);
        acc.x += v0 * __uint_as_float(x0.x << 16);
        acc.y += v0 * __uint_as_float(x0.x & 0xffff0000u);
        acc.z += v0 * __uint_as_float(x0.y << 16);
        acc.w += v0 * __uint_as_float(x0.y & 0xffff0000u);
    }
    float* o = out + ((size_t)g << 6) + lane * 4;
    float4 cur = *reinterpret_cast<const float4*>(o);
    acc.x += cur.x; acc.y += cur.y; acc.z += cur.z; acc.w += cur.w;
    *reinterpret_cast<float4*>(o) = acc;
}

// ---------------- MFMA concat-GEMM: out[r,:] = [a[r,:], b[r,:]] @ W ----------------
// Block = 256 threads = 4 waves; 64 rows/block (wave w owns rows w*16..+15, all 64 cols).
// A-frags straight from global (coalesced 16 rows x 64B); W^T bf16 in LDS, granule-swizzled.
// mfma_f32_16x16x32_bf16: A lane l: row=l&15, k=(l>>4)*8+i; B: col=l&15, same k packing;
// C/D: col=lane&15, row=(lane>>4)*4+reg  [HW-verified mapping].
template<bool FINAL>
__global__ __launch_bounds__(256) void gemm_mfma(
    const ushort* __restrict__ abf,   // bf16 [U,64] spmm result
    const ushort* __restrict__ bbf,   // bf16 [U,64] prev u
    const ushort* __restrict__ wtb,   // bf16 W^T [64,128] for this layer
    float* __restrict__ outf,         // FINAL: fp32 [U,64]
    ushort* __restrict__ outb,        // !FINAL: bf16 [U,64]
    int U)
{
    __shared__ ushort sWt[64 * 128];  // 16 KB, [col][k], granule-swizzled
    const int t = threadIdx.x;

    // stage W^T: granule g (8 bf16 = 16B), swizzle g' = g ^ (c&7)
    for (int i = t; i < 1024; i += 256) {
        int c = i >> 4, g = i & 15;
        uint4 v = *reinterpret_cast<const uint4*>(wtb + (size_t)c * 128 + g * 8);
        int gp = g ^ (c & 7);
        *reinterpret_cast<uint4*>(&sWt[c * 128 + gp * 8]) = v;
    }
    __syncthreads();

    const int w    = t >> 6;
    const int l    = t & 63;
    const int l16  = l & 15;          // A-row / B-col within tile
    const int ksub = l >> 4;          // k subgroup 0..3
    const int grow_base = blockIdx.x * 64 + w * 16;

    const int arow = min(grow_base + l16, U - 1);   // clamp: OOB rows never stored

    f32x4 acc[4] = {f32x4{0,0,0,0}, f32x4{0,0,0,0}, f32x4{0,0,0,0}, f32x4{0,0,0,0}};

    #pragma unroll
    for (int kk = 0; kk < 4; ++kk) {
        const int kof = kk * 32 + ksub * 8;         // 0..127 (concat-K)
        const ushort* asrc = (kk < 2) ? (abf + ((size_t)arow << 6) + kof)
                                      : (bbf + ((size_t)arow << 6) + (kof - 64));
        bf16x8 afrag = *reinterpret_cast<const bf16x8*>(asrc);
        #pragma unroll
        for (int ct = 0; ct < 4; ++ct) {
            int c  = ct * 16 + l16;
            int g  = kk * 4 + ksub;
            int gp = g ^ (c & 7);
            bf16x8 bfrag = *reinterpret_cast<const bf16x8*>(&sWt[c * 128 + gp * 8]);
            acc[ct] = __builtin_amdgcn_mfma_f32_16x16x32_bf16(afrag, bfrag, acc[ct], 0, 0, 0);
        }
    }

    #pragma unroll
    for (int ct = 0; ct < 4; ++ct) {
        #pragma unroll
        for (int j = 0; j < 4; ++j) {
            int grow = grow_base + ksub * 4 + j;
            int gcol = ct * 16 + l16;
            if (grow < U) {
                float v = acc[ct][j];
                if (FINAL) outf[((size_t)grow << 6) + gcol] = v;
                else       outb[((size_t)grow << 6) + gcol] = (ushort)bf16rn(v);
            }
        }
    }
}

extern "C" void kernel_launch(void* const* d_in, const int* in_sizes, int n_in,
                              void* d_out, int out_size, void* d_ws, size_t ws_size,
                              hipStream_t stream)
{
    const float* user_emb    = (const float*)d_in[0];
    const float* item_emb    = (const float*)d_in[1];
    const float* weights     = (const float*)d_in[2];
    const float* social_vals = (const float*)d_in[3];
    const float* inter_vals  = (const float*)d_in[4];
    const int*   social_rows = (const int*)d_in[5];
    const int*   social_cols = (const int*)d_in[6];
    const int*   inter_rows  = (const int*)d_in[7];
    const int*   inter_cols  = (const int*)d_in[8];

    const int D  = DD;
    const int U  = in_sizes[0] / D;
    const int I  = in_sizes[1] / D;
    const int L  = in_sizes[2] / (2 * D * D);
    const int ES = in_sizes[3];
    const int EI = in_sizes[4];

    float* out      = (float*)d_out;           // final_u [U, D]
    float* out_item = out + (size_t)U * D;     // item_emb passthrough [I, D]

    // ---- workspace layout ----
    char* p = (char*)d_ws;
    size_t off = 0;
    auto take = [&](size_t bytes) { char* r = p + off; off += align16(bytes); return r; };

    const int n2   = 2 * U;
    const int CB   = (n2 + RPCB - 1) >> CBSH;       // coarse buckets (<= 256)
    const int Etot = ES + EI;
    const int NBLK = (Etot + EPB - 1) / EPB;
    const int NH   = CB * NBLK;

    int*    row_ptr = (int*)take((size_t)(n2 + 1) * sizeof(int));
    int*    hmat    = (int*)take((size_t)NH * sizeof(int));
    int*    hS      = (int*)take((size_t)NH * sizeof(int));
    int*    bsums   = (int*)take(1024 * sizeof(int));
    uint2*  edges   = (uint2*)take((size_t)Etot * sizeof(uint2));
    uint2*  bedges  = (uint2*)take((size_t)Etot * sizeof(uint2));
    ushort* ubf     = (ushort*)take((size_t)U * D * sizeof(ushort));
    ushort* ibf     = (ushort*)take((size_t)I * D * sizeof(ushort));
    ushort* wtb     = (ushort*)take((size_t)L * 2 * D * D * sizeof(ushort));
    ushort* tmpA_bf = (ushort*)take((size_t)U * D * sizeof(ushort));
    ushort* uB_bf   = (ushort*)take((size_t)U * D * sizeof(ushort));
    ushort* uC_bf   = (ushort*)take((size_t)U * D * sizeof(ushort));

    // ---- CSR build: partition histogram -> scan -> partition scatter -> bucket finalize ----
    p1_hist<<<NBLK, 256, 0, stream>>>(social_rows, inter_rows, hmat, ES, EI, U, CB, NBLK);
    const int nb = (NH + 2047) / 2048;
    scan_partial<<<nb, 256, 0, stream>>>(hmat, hS, bsums, NH);
    scan_top<<<1, 1, 0, stream>>>(bsums, nb);
    scan_add<<<(NH + 255) / 256, 256, 0, stream>>>(hS, bsums, NH);
    p2_scatter<<<NBLK, 256, 0, stream>>>(
        social_rows, social_cols, social_vals,
        inter_rows, inter_cols, inter_vals,
        hS, bedges, ES, EI, U, CB, NBLK);
    p3_fin<<<CB, 256, 0, stream>>>(bedges, hS, row_ptr, edges, n2, Etot, CB, NBLK);

    // ---- bf16 conversions ----
    const int u8 = U * D / 8, i8 = I * D / 8;
    f32_to_bf16_2<<<(u8 + i8 + 255) / 256, 256, 0, stream>>>(
        user_emb, ubf, u8, item_emb, ibf, i8);
    const int nw = L * 2 * D * D;
    conv_w<<<(nw + 255) / 256, 256, 0, stream>>>(weights, wtb, nw);

    // ---- layers ----
    const int spmm_grid = ((U * 16) + 255) / 256;
    const int gemm_grid = (U + 63) / 64;
    const ushort* uprev = ubf;
    int which = 0;
    for (int k = 0; k < L; ++k) {
        const ushort* wk = wtb + (size_t)k * 2 * D * D;
        spmm_to_bf16<<<spmm_grid, 256, 0, stream>>>(row_ptr, edges, uprev, tmpA_bf, U);
        if (k == L - 1) {
            gemm_mfma<true><<<gemm_grid, 256, 0, stream>>>(
                tmpA_bf, uprev, wk, out, (ushort*)nullptr, U);
        } else {
            ushort* unext = which ? uC_bf : uB_bf;
            gemm_mfma<false><<<gemm_grid, 256, 0, stream>>>(
                tmpA_bf, uprev, wk, (float*)nullptr, unext, U);
            uprev = unext;
            which ^= 1;
        }
    }

    // final_u += A_inter @ item_emb (bf16 gather, fp32 accumulate into d_out)
    spmm_add_f32<<<spmm_grid, 256, 0, stream>>>(row_ptr + U, edges, ibf, out, U);

    // output 1: item_emb passthrough
    hipMemcpyAsync(out_item, item_emb, (size_t)I * D * sizeof(float),
                   hipMemcpyDeviceToDevice, stream);
}

// Round 9
// 231.823 us; speedup vs baseline: 7.0775x; 1.0708x over previous
//
#include <hip/hip_runtime.h>

#define DD 64        // embedding dim
#define RPCB 256     // rows per coarse bucket
#define CBSH 8       // log2(RPCB)
#define NBLK_P 512   // partition blocks (p1/p2)

static inline size_t align16(size_t x) { return (x + 15) & ~(size_t)15; }

__device__ __forceinline__ unsigned bf16rn(float f) {
    unsigned u = __float_as_uint(f);
    return (u + 0x7fffu + ((u >> 16) & 1u)) >> 16;   // RNE
}

typedef __attribute__((ext_vector_type(8))) short bf16x8;  // 8 bf16 (4 VGPRs)
typedef __attribute__((ext_vector_type(4))) float f32x4;   // 4 fp32 acc

// ---------------- P1: per-block histogram over coarse buckets ----------------
__global__ __launch_bounds__(1024) void p1_hist(
    const int* __restrict__ srows, const int* __restrict__ irows,
    int* __restrict__ hmat, int ES, int EI, int U, int CB, int EPB)
{
    __shared__ int hist[1024];         // CB <= 1024 (U <= 131072)
    const int b = blockIdx.x, t = threadIdx.x;
    for (int i = t; i < CB; i += 1024) hist[i] = 0;
    __syncthreads();
    const int e0 = b * EPB, e1 = min(e0 + EPB, ES + EI);
    for (int e = e0 + t; e < e1; e += 1024) {
        int row = (e < ES) ? srows[e] : U + irows[e - ES];
        atomicAdd(&hist[row >> CBSH], 1);
    }
    __syncthreads();
    for (int i = t; i < CB; i += 1024) hmat[(size_t)i * NBLK_P + b] = hist[i];
}

// ---------------- scan helpers ----------------
__global__ __launch_bounds__(256) void scan_partial(
    const int* __restrict__ in, int* __restrict__ out, int* __restrict__ bsums, int n)
{
    __shared__ int sh[256];
    int base = blockIdx.x * 2048 + threadIdx.x * 8;
    int v[8];
    int tsum = 0;
    #pragma unroll
    for (int j = 0; j < 8; ++j) {
        int idx = base + j;
        int x = (idx < n) ? in[idx] : 0;
        v[j] = tsum;
        tsum += x;
    }
    sh[threadIdx.x] = tsum;
    __syncthreads();
    for (int off = 1; off < 256; off <<= 1) {
        int t = (threadIdx.x >= off) ? sh[threadIdx.x - off] : 0;
        __syncthreads();
        sh[threadIdx.x] += t;
        __syncthreads();
    }
    int texc = sh[threadIdx.x] - tsum;
    #pragma unroll
    for (int j = 0; j < 8; ++j) {
        int idx = base + j;
        if (idx < n) out[idx] = texc + v[j];
    }
    if (threadIdx.x == 255) bsums[blockIdx.x] = sh[255];
}

__global__ void scan_top(int* bsums, int nb)
{
    int run = 0;
    for (int i = 0; i < nb; ++i) { int t = bsums[i]; bsums[i] = run; run += t; }
}

__global__ __launch_bounds__(256) void scan_add(
    int* __restrict__ out, const int* __restrict__ bsums, int n)
{
    int i = blockIdx.x * 256 + threadIdx.x;
    if (i < n) out[i] += bsums[i >> 11];
}

// ---------------- P2: partition scatter into per-(bucket,block) exclusive ranges ----------------
// payload: .x = (row_lo << 17) | col  (row_lo 8b, col <= 17b), .y = fp32 val bits
__global__ __launch_bounds__(1024) void p2_scatter(
    const int* __restrict__ srows, const int* __restrict__ scols, const float* __restrict__ svals,
    const int* __restrict__ irows, const int* __restrict__ icols, const float* __restrict__ ivals,
    const int* __restrict__ hS, uint2* __restrict__ bedges,
    int ES, int EI, int U, int CB, int EPB)
{
    __shared__ int cur[1024];
    const int b = blockIdx.x, t = threadIdx.x;
    for (int i = t; i < CB; i += 1024) cur[i] = hS[(size_t)i * NBLK_P + b];
    __syncthreads();
    const int e0 = b * EPB, e1 = min(e0 + EPB, ES + EI);
    for (int e = e0 + t; e < e1; e += 1024) {
        int row, col; unsigned val;
        if (e < ES) { row = srows[e]; col = scols[e]; val = __float_as_uint(svals[e]); }
        else {
            int i = e - ES;
            row = U + irows[i]; col = icols[i]; val = __float_as_uint(ivals[i]);
        }
        int slot = atomicAdd(&cur[row >> CBSH], 1);
        bedges[slot] = make_uint2(((unsigned)(row & (RPCB - 1)) << 17) | (unsigned)col, val);
    }
}

// ---------------- P3: per-bucket finalize -> row_ptr + exact CSR slots ----------------
__global__ __launch_bounds__(256) void p3_fin(
    const uint2* __restrict__ bedges, const int* __restrict__ hS,
    int* __restrict__ row_ptr, uint2* __restrict__ edges,
    int n2, int Etot, int CB)
{
    __shared__ int cnt[RPCB];
    __shared__ int sh[256];
    const int cb = blockIdx.x, t = threadIdx.x;
    const int r0 = cb << CBSH;
    const int s = hS[(size_t)cb * NBLK_P];
    const int e = (cb == CB - 1) ? Etot : hS[(size_t)(cb + 1) * NBLK_P];

    cnt[t] = 0;
    __syncthreads();
    for (int i = s + t; i < e; i += 256) atomicAdd(&cnt[bedges[i].x >> 17], 1);
    __syncthreads();

    int c = cnt[t];
    sh[t] = c;
    __syncthreads();
    for (int off = 1; off < 256; off <<= 1) {
        int v = (t >= off) ? sh[t - off] : 0;
        __syncthreads();
        sh[t] += v;
        __syncthreads();
    }
    int excl = sh[t] - c;
    int v = s + excl;
    cnt[t] = v;                         // becomes cursor
    int gr = r0 + t;
    if (gr < n2) row_ptr[gr] = v;
    if (cb == CB - 1 && t == 0) row_ptr[n2] = Etot;
    __syncthreads();

    for (int i = s + t; i < e; i += 256) {
        uint2 ev = bedges[i];
        int r = ev.x >> 17;
        int slot = atomicAdd(&cnt[r], 1);
        edges[slot] = make_uint2(ev.x & 0x1FFFFu, ev.y);
    }
}

// ---------------- fp32 -> bf16 tables (user + item in one launch) ----------------
__global__ __launch_bounds__(256) void f32_to_bf16_2(
    const float* __restrict__ inA, ushort* __restrict__ outA, int n8A,
    const float* __restrict__ inB, ushort* __restrict__ outB, int n8B)
{
    int i = blockIdx.x * 256 + threadIdx.x;
    const float* in; ushort* out;
    if (i < n8A) { in = inA; out = outA; }
    else if (i < n8A + n8B) { i -= n8A; in = inB; out = outB; }
    else return;
    const float4* p = reinterpret_cast<const float4*>(in) + (size_t)i * 2;
    float4 A = p[0], B = p[1];
    uint4 r;
    r.x = bf16rn(A.x) | (bf16rn(A.y) << 16);
    r.y = bf16rn(A.z) | (bf16rn(A.w) << 16);
    r.z = bf16rn(B.x) | (bf16rn(B.y) << 16);
    r.w = bf16rn(B.z) | (bf16rn(B.w) << 16);
    reinterpret_cast<uint4*>(out)[i] = r;
}

// ---------------- weights: fp32 [L][128][64] -> bf16 W^T [L][64][128] ----------------
__global__ __launch_bounds__(256) void conv_w(
    const float* __restrict__ w, ushort* __restrict__ wtb, int n)  // n = L*8192
{
    int idx = blockIdx.x * 256 + threadIdx.x;
    if (idx >= n) return;
    int l = idx >> 13;
    int r = idx & 8191;
    int c = r >> 7;          // col 0..63
    int k = r & 127;         // k   0..127
    wtb[idx] = (ushort)bf16rn(w[(size_t)l * 8192 + k * 64 + c]);
}

// ---------------- SpMM (CSR row-gather, bf16 source, fp32 accumulate) ----------------
__device__ __forceinline__ void fmadd8(float4& acc, unsigned vb, uint2 x)
{
    float v = __uint_as_float(vb);
    acc.x += v * __uint_as_float(x.x << 16);
    acc.y += v * __uint_as_float(x.x & 0xffff0000u);
    acc.z += v * __uint_as_float(x.y << 16);
    acc.w += v * __uint_as_float(x.y & 0xffff0000u);
}

// MODE 0: write bf16; MODE 1: add into fp32 out
template <int MODE>
__global__ __launch_bounds__(256) void spmm_g(
    const int* __restrict__ row_ptr, const uint2* __restrict__ edges,
    const ushort* __restrict__ xb,   // bf16 [nx,64]
    ushort* __restrict__ outb, float* __restrict__ outf, int nrows)
{
    int g    = (blockIdx.x * 256 + threadIdx.x) >> 4;
    int lane = threadIdx.x & 15;
    if (g >= nrows) return;
    int s = row_ptr[g], e = row_ptr[g + 1];
    float4 acc = make_float4(0.f, 0.f, 0.f, 0.f);
    int i = s;
    for (; i + 3 < e; i += 4) {
        uint2 e0 = edges[i], e1 = edges[i + 1], e2 = edges[i + 2], e3 = edges[i + 3];
        uint2 x0 = *reinterpret_cast<const uint2*>(xb + ((size_t)e0.x << 6) + lane * 4);
        uint2 x1 = *reinterpret_cast<const uint2*>(xb + ((size_t)e1.x << 6) + lane * 4);
        uint2 x2 = *reinterpret_cast<const uint2*>(xb + ((size_t)e2.x << 6) + lane * 4);
        uint2 x3 = *reinterpret_cast<const uint2*>(xb + ((size_t)e3.x << 6) + lane * 4);
        fmadd8(acc, e0.y, x0);
        fmadd8(acc, e1.y, x1);
        fmadd8(acc, e2.y, x2);
        fmadd8(acc, e3.y, x3);
    }
    for (; i < e; ++i) {
        uint2 e0 = edges[i];
        uint2 x0 = *reinterpret_cast<const uint2*>(xb + ((size_t)e0.x << 6) + lane * 4);
        fmadd8(acc, e0.y, x0);
    }
    if (MODE == 0) {
        unsigned p0 = bf16rn(acc.x) | (bf16rn(acc.y) << 16);
        unsigned p1 = bf16rn(acc.z) | (bf16rn(acc.w) << 16);
        *reinterpret_cast<uint2*>(outb + ((size_t)g << 6) + lane * 4) = make_uint2(p0, p1);
    } else {
        float* o = outf + ((size_t)g << 6) + lane * 4;
        float4 cur = *reinterpret_cast<const float4*>(o);
        acc.x += cur.x; acc.y += cur.y; acc.z += cur.z; acc.w += cur.w;
        *reinterpret_cast<float4*>(o) = acc;
    }
}

// ---------------- MFMA concat-GEMM: out[r,:] = [a[r,:], b[r,:]] @ W ----------------
// Block = 256 threads = 4 waves; 64 rows/block. A-frags from global; W^T bf16 in LDS,
// granule-swizzled. C/D mapping: col=lane&15, row=(lane>>4)*4+reg [HW-verified].
template<bool FINAL>
__global__ __launch_bounds__(256) void gemm_mfma(
    const ushort* __restrict__ abf,   // bf16 [U,64] spmm result
    const ushort* __restrict__ bbf,   // bf16 [U,64] prev u
    const ushort* __restrict__ wtb,   // bf16 W^T [64,128] for this layer
    float* __restrict__ outf,         // FINAL: fp32 [U,64]
    ushort* __restrict__ outb,        // !FINAL: bf16 [U,64]
    int U)
{
    __shared__ ushort sWt[64 * 128];  // 16 KB, [col][k], granule-swizzled
    const int t = threadIdx.x;

    for (int i = t; i < 1024; i += 256) {
        int c = i >> 4, g = i & 15;
        uint4 v = *reinterpret_cast<const uint4*>(wtb + (size_t)c * 128 + g * 8);
        int gp = g ^ (c & 7);
        *reinterpret_cast<uint4*>(&sWt[c * 128 + gp * 8]) = v;
    }
    __syncthreads();

    const int w    = t >> 6;
    const int l    = t & 63;
    const int l16  = l & 15;
    const int ksub = l >> 4;
    const int grow_base = blockIdx.x * 64 + w * 16;

    const int arow = min(grow_base + l16, U - 1);

    f32x4 acc[4] = {f32x4{0,0,0,0}, f32x4{0,0,0,0}, f32x4{0,0,0,0}, f32x4{0,0,0,0}};

    #pragma unroll
    for (int kk = 0; kk < 4; ++kk) {
        const int kof = kk * 32 + ksub * 8;
        const ushort* asrc = (kk < 2) ? (abf + ((size_t)arow << 6) + kof)
                                      : (bbf + ((size_t)arow << 6) + (kof - 64));
        bf16x8 afrag = *reinterpret_cast<const bf16x8*>(asrc);
        #pragma unroll
        for (int ct = 0; ct < 4; ++ct) {
            int c  = ct * 16 + l16;
            int g  = kk * 4 + ksub;
            int gp = g ^ (c & 7);
            bf16x8 bfrag = *reinterpret_cast<const bf16x8*>(&sWt[c * 128 + gp * 8]);
            acc[ct] = __builtin_amdgcn_mfma_f32_16x16x32_bf16(afrag, bfrag, acc[ct], 0, 0, 0);
        }
    }

    #pragma unroll
    for (int ct = 0; ct < 4; ++ct) {
        #pragma unroll
        for (int j = 0; j < 4; ++j) {
            int grow = grow_base + ksub * 4 + j;
            int gcol = ct * 16 + l16;
            if (grow < U) {
                float v = acc[ct][j];
                if (FINAL) outf[((size_t)grow << 6) + gcol] = v;
                else       outb[((size_t)grow << 6) + gcol] = (ushort)bf16rn(v);
            }
        }
    }
}

extern "C" void kernel_launch(void* const* d_in, const int* in_sizes, int n_in,
                              void* d_out, int out_size, void* d_ws, size_t ws_size,
                              hipStream_t stream)
{
    const float* user_emb    = (const float*)d_in[0];
    const float* item_emb    = (const float*)d_in[1];
    const float* weights     = (const float*)d_in[2];
    const float* social_vals = (const float*)d_in[3];
    const float* inter_vals  = (const float*)d_in[4];
    const int*   social_rows = (const int*)d_in[5];
    const int*   social_cols = (const int*)d_in[6];
    const int*   inter_rows  = (const int*)d_in[7];
    const int*   inter_cols  = (const int*)d_in[8];

    const int D  = DD;
    const int U  = in_sizes[0] / D;
    const int I  = in_sizes[1] / D;
    const int L  = in_sizes[2] / (2 * D * D);
    const int ES = in_sizes[3];
    const int EI = in_sizes[4];

    float* out      = (float*)d_out;           // final_u [U, D]
    float* out_item = out + (size_t)U * D;     // item_emb passthrough [I, D]

    // ---- workspace layout ----
    char* p = (char*)d_ws;
    size_t off = 0;
    auto take = [&](size_t bytes) { char* r = p + off; off += align16(bytes); return r; };

    const int n2   = 2 * U;
    const int CB   = (n2 + RPCB - 1) >> CBSH;       // coarse buckets (<= 1024)
    const int Etot = ES + EI;
    const int EPB  = (Etot + NBLK_P - 1) / NBLK_P;  // edges per partition block
    const int NH   = CB * NBLK_P;

    int*    row_ptr = (int*)take((size_t)(n2 + 1) * sizeof(int));
    int*    hmat    = (int*)take((size_t)NH * sizeof(int));
    int*    hS      = (int*)take((size_t)NH * sizeof(int));
    int*    bsums   = (int*)take(1024 * sizeof(int));
    uint2*  edges   = (uint2*)take((size_t)Etot * sizeof(uint2));
    uint2*  bedges  = (uint2*)take((size_t)Etot * sizeof(uint2));
    ushort* ubf     = (ushort*)take((size_t)U * D * sizeof(ushort));
    ushort* ibf     = (ushort*)take((size_t)I * D * sizeof(ushort));
    ushort* wtb     = (ushort*)take((size_t)L * 2 * D * D * sizeof(ushort));
    ushort* tmpA_bf = (ushort*)take((size_t)U * D * sizeof(ushort));
    ushort* uB_bf   = (ushort*)take((size_t)U * D * sizeof(ushort));
    ushort* uC_bf   = (ushort*)take((size_t)U * D * sizeof(ushort));

    // ---- CSR build: partition histogram -> scan -> partition scatter -> bucket finalize ----
    p1_hist<<<NBLK_P, 1024, 0, stream>>>(social_rows, inter_rows, hmat, ES, EI, U, CB, EPB);
    const int nb = (NH + 2047) / 2048;
    scan_partial<<<nb, 256, 0, stream>>>(hmat, hS, bsums, NH);
    scan_top<<<1, 1, 0, stream>>>(bsums, nb);
    scan_add<<<(NH + 255) / 256, 256, 0, stream>>>(hS, bsums, NH);
    p2_scatter<<<NBLK_P, 1024, 0, stream>>>(
        social_rows, social_cols, social_vals,
        inter_rows, inter_cols, inter_vals,
        hS, bedges, ES, EI, U, CB, EPB);
    p3_fin<<<CB, 256, 0, stream>>>(bedges, hS, row_ptr, edges, n2, Etot, CB);

    // ---- bf16 conversions ----
    const int u8 = U * D / 8, i8 = I * D / 8;
    f32_to_bf16_2<<<(u8 + i8 + 255) / 256, 256, 0, stream>>>(
        user_emb, ubf, u8, item_emb, ibf, i8);
    const int nw = L * 2 * D * D;
    conv_w<<<(nw + 255) / 256, 256, 0, stream>>>(weights, wtb, nw);

    // ---- layers ----
    const int spmm_grid = ((U * 16) + 255) / 256;
    const int gemm_grid = (U + 63) / 64;
    const ushort* uprev = ubf;
    int which = 0;
    for (int k = 0; k < L; ++k) {
        const ushort* wk = wtb + (size_t)k * 2 * D * D;
        spmm_g<0><<<spmm_grid, 256, 0, stream>>>(
            row_ptr, edges, uprev, tmpA_bf, (float*)nullptr, U);
        if (k == L - 1) {
            gemm_mfma<true><<<gemm_grid, 256, 0, stream>>>(
                tmpA_bf, uprev, wk, out, (ushort*)nullptr, U);
        } else {
            ushort* unext = which ? uC_bf : uB_bf;
            gemm_mfma<false><<<gemm_grid, 256, 0, stream>>>(
                tmpA_bf, uprev, wk, (float*)nullptr, unext, U);
            uprev = unext;
            which ^= 1;
        }
    }

    // final_u += A_inter @ item_emb (bf16 gather, fp32 accumulate into d_out)
    spmm_g<1><<<spmm_grid, 256, 0, stream>>>(
        row_ptr + U, edges, ibf, (ushort*)nullptr, out, U);

    // output 1: item_emb passthrough
    hipMemcpyAsync(out_item, item_emb, (size_t)I * D * sizeof(float),
                   hipMemcpyDeviceToDevice, stream);
}

// Round 10
// 230.170 us; speedup vs baseline: 7.1284x; 1.0072x over previous
//
#include <hip/hip_runtime.h>

#define DD 64        // embedding dim
#define RPCB 256     // rows per coarse bucket
#define CBSH 8       // log2(RPCB)
#define NBLK_P 512   // partition blocks (p1/p2)

static inline size_t align16(size_t x) { return (x + 15) & ~(size_t)15; }

__device__ __forceinline__ unsigned bf16rn(float f) {
    unsigned u = __float_as_uint(f);
    return (u + 0x7fffu + ((u >> 16) & 1u)) >> 16;   // RNE
}

typedef __attribute__((ext_vector_type(8))) short bf16x8;  // 8 bf16 (4 VGPRs)
typedef __attribute__((ext_vector_type(4))) float f32x4;   // 4 fp32 acc

// ---------------- P1: per-block histogram over coarse buckets ----------------
__global__ __launch_bounds__(1024) void p1_hist(
    const int* __restrict__ srows, const int* __restrict__ irows,
    int* __restrict__ hmat, int ES, int EI, int U, int CB, int EPB)
{
    __shared__ int hist[1024];         // CB <= 1024 (U <= 131072)
    const int b = blockIdx.x, t = threadIdx.x;
    for (int i = t; i < CB; i += 1024) hist[i] = 0;
    __syncthreads();
    const int e0 = b * EPB, e1 = min(e0 + EPB, ES + EI);
    for (int e = e0 + t; e < e1; e += 1024) {
        int row = (e < ES) ? srows[e] : U + irows[e - ES];
        atomicAdd(&hist[row >> CBSH], 1);
    }
    __syncthreads();
    for (int i = t; i < CB; i += 1024) hmat[(size_t)i * NBLK_P + b] = hist[i];
}

// ---------------- scan helpers ----------------
__global__ __launch_bounds__(256) void scan_partial(
    const int* __restrict__ in, int* __restrict__ out, int* __restrict__ bsums, int n)
{
    __shared__ int sh[256];
    int base = blockIdx.x * 2048 + threadIdx.x * 8;
    int v[8];
    int tsum = 0;
    #pragma unroll
    for (int j = 0; j < 8; ++j) {
        int idx = base + j;
        int x = (idx < n) ? in[idx] : 0;
        v[j] = tsum;
        tsum += x;
    }
    sh[threadIdx.x] = tsum;
    __syncthreads();
    for (int off = 1; off < 256; off <<= 1) {
        int t = (threadIdx.x >= off) ? sh[threadIdx.x - off] : 0;
        __syncthreads();
        sh[threadIdx.x] += t;
        __syncthreads();
    }
    int texc = sh[threadIdx.x] - tsum;
    #pragma unroll
    for (int j = 0; j < 8; ++j) {
        int idx = base + j;
        if (idx < n) out[idx] = texc + v[j];
    }
    if (threadIdx.x == 255) bsums[blockIdx.x] = sh[255];
}

__global__ void scan_top(int* bsums, int nb)
{
    int run = 0;
    for (int i = 0; i < nb; ++i) { int t = bsums[i]; bsums[i] = run; run += t; }
}

__global__ __launch_bounds__(256) void scan_add(
    int* __restrict__ out, const int* __restrict__ bsums, int n)
{
    int i = blockIdx.x * 256 + threadIdx.x;
    if (i < n) out[i] += bsums[i >> 11];
}

// ---------------- P2: partition scatter into per-(bucket,block) exclusive ranges ----------------
// payload: .x = (row_lo << 17) | col  (row_lo 8b, col <= 17b), .y = fp32 val bits
__global__ __launch_bounds__(1024) void p2_scatter(
    const int* __restrict__ srows, const int* __restrict__ scols, const float* __restrict__ svals,
    const int* __restrict__ irows, const int* __restrict__ icols, const float* __restrict__ ivals,
    const int* __restrict__ hS, uint2* __restrict__ bedges,
    int ES, int EI, int U, int CB, int EPB)
{
    __shared__ int cur[1024];
    const int b = blockIdx.x, t = threadIdx.x;
    for (int i = t; i < CB; i += 1024) cur[i] = hS[(size_t)i * NBLK_P + b];
    __syncthreads();
    const int e0 = b * EPB, e1 = min(e0 + EPB, ES + EI);
    for (int e = e0 + t; e < e1; e += 1024) {
        int row, col; unsigned val;
        if (e < ES) { row = srows[e]; col = scols[e]; val = __float_as_uint(svals[e]); }
        else {
            int i = e - ES;
            row = U + irows[i]; col = icols[i]; val = __float_as_uint(ivals[i]);
        }
        int slot = atomicAdd(&cur[row >> CBSH], 1);
        bedges[slot] = make_uint2(((unsigned)(row & (RPCB - 1)) << 17) | (unsigned)col, val);
    }
}

// ---------------- P3: per-bucket finalize -> row_ptr + exact CSR slots ----------------
__global__ __launch_bounds__(256) void p3_fin(
    const uint2* __restrict__ bedges, const int* __restrict__ hS,
    int* __restrict__ row_ptr, uint2* __restrict__ edges,
    int n2, int Etot, int CB)
{
    __shared__ int cnt[RPCB];
    __shared__ int sh[256];
    const int cb = blockIdx.x, t = threadIdx.x;
    const int r0 = cb << CBSH;
    const int s = hS[(size_t)cb * NBLK_P];
    const int e = (cb == CB - 1) ? Etot : hS[(size_t)(cb + 1) * NBLK_P];

    cnt[t] = 0;
    __syncthreads();
    for (int i = s + t; i < e; i += 256) atomicAdd(&cnt[bedges[i].x >> 17], 1);
    __syncthreads();

    int c = cnt[t];
    sh[t] = c;
    __syncthreads();
    for (int off = 1; off < 256; off <<= 1) {
        int v = (t >= off) ? sh[t - off] : 0;
        __syncthreads();
        sh[t] += v;
        __syncthreads();
    }
    int excl = sh[t] - c;
    int v = s + excl;
    cnt[t] = v;                         // becomes cursor
    int gr = r0 + t;
    if (gr < n2) row_ptr[gr] = v;
    if (cb == CB - 1 && t == 0) row_ptr[n2] = Etot;
    __syncthreads();

    for (int i = s + t; i < e; i += 256) {
        uint2 ev = bedges[i];
        int r = ev.x >> 17;
        int slot = atomicAdd(&cnt[r], 1);
        edges[slot] = make_uint2(ev.x & 0x1FFFFu, ev.y);
    }
}

// ---------------- fp32 -> bf16 tables; item half also writes fp32 passthrough ----------------
__global__ __launch_bounds__(256) void f32_to_bf16_2(
    const float* __restrict__ inA, ushort* __restrict__ outA, int n8A,
    const float* __restrict__ inB, ushort* __restrict__ outB,
    float* __restrict__ passB, int n8B)
{
    int i = blockIdx.x * 256 + threadIdx.x;
    const float* in; ushort* out; float* pass = nullptr;
    if (i < n8A) { in = inA; out = outA; }
    else if (i < n8A + n8B) { i -= n8A; in = inB; out = outB; pass = passB; }
    else return;
    const float4* p = reinterpret_cast<const float4*>(in) + (size_t)i * 2;
    float4 A = p[0], B = p[1];
    uint4 r;
    r.x = bf16rn(A.x) | (bf16rn(A.y) << 16);
    r.y = bf16rn(A.z) | (bf16rn(A.w) << 16);
    r.z = bf16rn(B.x) | (bf16rn(B.y) << 16);
    r.w = bf16rn(B.z) | (bf16rn(B.w) << 16);
    reinterpret_cast<uint4*>(out)[i] = r;
    if (pass) {
        float4* q = reinterpret_cast<float4*>(pass) + (size_t)i * 2;
        q[0] = A; q[1] = B;
    }
}

// ---------------- weights: fp32 [L][128][64] -> bf16 W^T [L][64][128] ----------------
__global__ __launch_bounds__(256) void conv_w(
    const float* __restrict__ w, ushort* __restrict__ wtb, int n)  // n = L*8192
{
    int idx = blockIdx.x * 256 + threadIdx.x;
    if (idx >= n) return;
    int l = idx >> 13;
    int r = idx & 8191;
    int c = r >> 7;          // col 0..63
    int k = r & 127;         // k   0..127
    wtb[idx] = (ushort)bf16rn(w[(size_t)l * 8192 + k * 64 + c]);
}

// ---------------- SpMM (CSR row-gather, bf16 source, fp32 accumulate) ----------------
// 8 lanes per destination row; each lane owns 8 of the 64 columns (16B uint4 gather/lane).
__device__ __forceinline__ void fmadd16(float4& a0, float4& a1, unsigned vb, uint4 x)
{
    float v = __uint_as_float(vb);
    a0.x += v * __uint_as_float(x.x << 16);
    a0.y += v * __uint_as_float(x.x & 0xffff0000u);
    a0.z += v * __uint_as_float(x.y << 16);
    a0.w += v * __uint_as_float(x.y & 0xffff0000u);
    a1.x += v * __uint_as_float(x.z << 16);
    a1.y += v * __uint_as_float(x.z & 0xffff0000u);
    a1.z += v * __uint_as_float(x.w << 16);
    a1.w += v * __uint_as_float(x.w & 0xffff0000u);
}

// MODE 0: write bf16; MODE 1: add into fp32 out
template <int MODE>
__global__ __launch_bounds__(256) void spmm_g(
    const int* __restrict__ row_ptr, const uint2* __restrict__ edges,
    const ushort* __restrict__ xb,   // bf16 [nx,64]
    ushort* __restrict__ outb, float* __restrict__ outf, int nrows)
{
    int g    = (blockIdx.x * 256 + threadIdx.x) >> 3;
    int lane = threadIdx.x & 7;
    if (g >= nrows) return;
    int s = row_ptr[g], e = row_ptr[g + 1];
    float4 a0 = make_float4(0.f, 0.f, 0.f, 0.f);
    float4 a1 = make_float4(0.f, 0.f, 0.f, 0.f);
    int i = s;
    for (; i + 3 < e; i += 4) {
        uint2 e0 = edges[i], e1 = edges[i + 1], e2 = edges[i + 2], e3 = edges[i + 3];
        uint4 x0 = *reinterpret_cast<const uint4*>(xb + ((size_t)e0.x << 6) + lane * 8);
        uint4 x1 = *reinterpret_cast<const uint4*>(xb + ((size_t)e1.x << 6) + lane * 8);
        uint4 x2 = *reinterpret_cast<const uint4*>(xb + ((size_t)e2.x << 6) + lane * 8);
        uint4 x3 = *reinterpret_cast<const uint4*>(xb + ((size_t)e3.x << 6) + lane * 8);
        fmadd16(a0, a1, e0.y, x0);
        fmadd16(a0, a1, e1.y, x1);
        fmadd16(a0, a1, e2.y, x2);
        fmadd16(a0, a1, e3.y, x3);
    }
    for (; i < e; ++i) {
        uint2 e0 = edges[i];
        uint4 x0 = *reinterpret_cast<const uint4*>(xb + ((size_t)e0.x << 6) + lane * 8);
        fmadd16(a0, a1, e0.y, x0);
    }
    if (MODE == 0) {
        uint4 pk;
        pk.x = bf16rn(a0.x) | (bf16rn(a0.y) << 16);
        pk.y = bf16rn(a0.z) | (bf16rn(a0.w) << 16);
        pk.z = bf16rn(a1.x) | (bf16rn(a1.y) << 16);
        pk.w = bf16rn(a1.z) | (bf16rn(a1.w) << 16);
        *reinterpret_cast<uint4*>(outb + ((size_t)g << 6) + lane * 8) = pk;
    } else {
        float* o = outf + ((size_t)g << 6) + lane * 8;
        float4 c0 = *reinterpret_cast<const float4*>(o);
        float4 c1 = *reinterpret_cast<const float4*>(o + 4);
        a0.x += c0.x; a0.y += c0.y; a0.z += c0.z; a0.w += c0.w;
        a1.x += c1.x; a1.y += c1.y; a1.z += c1.z; a1.w += c1.w;
        *reinterpret_cast<float4*>(o)     = a0;
        *reinterpret_cast<float4*>(o + 4) = a1;
    }
}

// ---------------- MFMA concat-GEMM: out[r,:] = [a[r,:], b[r,:]] @ W ----------------
// Block = 256 threads = 4 waves; 64 rows/block. A-frags from global; W^T bf16 in LDS,
// granule-swizzled. C/D mapping: col=lane&15, row=(lane>>4)*4+reg [HW-verified].
template<bool FINAL>
__global__ __launch_bounds__(256) void gemm_mfma(
    const ushort* __restrict__ abf,   // bf16 [U,64] spmm result
    const ushort* __restrict__ bbf,   // bf16 [U,64] prev u
    const ushort* __restrict__ wtb,   // bf16 W^T [64,128] for this layer
    float* __restrict__ outf,         // FINAL: fp32 [U,64]
    ushort* __restrict__ outb,        // !FINAL: bf16 [U,64]
    int U)
{
    __shared__ ushort sWt[64 * 128];  // 16 KB, [col][k], granule-swizzled
    const int t = threadIdx.x;

    for (int i = t; i < 1024; i += 256) {
        int c = i >> 4, g = i & 15;
        uint4 v = *reinterpret_cast<const uint4*>(wtb + (size_t)c * 128 + g * 8);
        int gp = g ^ (c & 7);
        *reinterpret_cast<uint4*>(&sWt[c * 128 + gp * 8]) = v;
    }
    __syncthreads();

    const int w    = t >> 6;
    const int l    = t & 63;
    const int l16  = l & 15;
    const int ksub = l >> 4;
    const int grow_base = blockIdx.x * 64 + w * 16;

    const int arow = min(grow_base + l16, U - 1);

    f32x4 acc[4] = {f32x4{0,0,0,0}, f32x4{0,0,0,0}, f32x4{0,0,0,0}, f32x4{0,0,0,0}};

    #pragma unroll
    for (int kk = 0; kk < 4; ++kk) {
        const int kof = kk * 32 + ksub * 8;
        const ushort* asrc = (kk < 2) ? (abf + ((size_t)arow << 6) + kof)
                                      : (bbf + ((size_t)arow << 6) + (kof - 64));
        bf16x8 afrag = *reinterpret_cast<const bf16x8*>(asrc);
        #pragma unroll
        for (int ct = 0; ct < 4; ++ct) {
            int c  = ct * 16 + l16;
            int g  = kk * 4 + ksub;
            int gp = g ^ (c & 7);
            bf16x8 bfrag = *reinterpret_cast<const bf16x8*>(&sWt[c * 128 + gp * 8]);
            acc[ct] = __builtin_amdgcn_mfma_f32_16x16x32_bf16(afrag, bfrag, acc[ct], 0, 0, 0);
        }
    }

    #pragma unroll
    for (int ct = 0; ct < 4; ++ct) {
        #pragma unroll
        for (int j = 0; j < 4; ++j) {
            int grow = grow_base + ksub * 4 + j;
            int gcol = ct * 16 + l16;
            if (grow < U) {
                float v = acc[ct][j];
                if (FINAL) outf[((size_t)grow << 6) + gcol] = v;
                else       outb[((size_t)grow << 6) + gcol] = (ushort)bf16rn(v);
            }
        }
    }
}

extern "C" void kernel_launch(void* const* d_in, const int* in_sizes, int n_in,
                              void* d_out, int out_size, void* d_ws, size_t ws_size,
                              hipStream_t stream)
{
    const float* user_emb    = (const float*)d_in[0];
    const float* item_emb    = (const float*)d_in[1];
    const float* weights     = (const float*)d_in[2];
    const float* social_vals = (const float*)d_in[3];
    const float* inter_vals  = (const float*)d_in[4];
    const int*   social_rows = (const int*)d_in[5];
    const int*   social_cols = (const int*)d_in[6];
    const int*   inter_rows  = (const int*)d_in[7];
    const int*   inter_cols  = (const int*)d_in[8];

    const int D  = DD;
    const int U  = in_sizes[0] / D;
    const int I  = in_sizes[1] / D;
    const int L  = in_sizes[2] / (2 * D * D);
    const int ES = in_sizes[3];
    const int EI = in_sizes[4];

    float* out      = (float*)d_out;           // final_u [U, D]
    float* out_item = out + (size_t)U * D;     // item_emb passthrough [I, D]

    // ---- workspace layout ----
    char* p = (char*)d_ws;
    size_t off = 0;
    auto take = [&](size_t bytes) { char* r = p + off; off += align16(bytes); return r; };

    const int n2   = 2 * U;
    const int CB   = (n2 + RPCB - 1) >> CBSH;       // coarse buckets (<= 1024)
    const int Etot = ES + EI;
    const int EPB  = (Etot + NBLK_P - 1) / NBLK_P;  // edges per partition block
    const int NH   = CB * NBLK_P;

    int*    row_ptr = (int*)take((size_t)(n2 + 1) * sizeof(int));
    int*    hmat    = (int*)take((size_t)NH * sizeof(int));
    int*    hS      = (int*)take((size_t)NH * sizeof(int));
    int*    bsums   = (int*)take(1024 * sizeof(int));
    uint2*  edges   = (uint2*)take((size_t)Etot * sizeof(uint2));
    uint2*  bedges  = (uint2*)take((size_t)Etot * sizeof(uint2));
    ushort* ubf     = (ushort*)take((size_t)U * D * sizeof(ushort));
    ushort* ibf     = (ushort*)take((size_t)I * D * sizeof(ushort));
    ushort* wtb     = (ushort*)take((size_t)L * 2 * D * D * sizeof(ushort));
    ushort* tmpA_bf = (ushort*)take((size_t)U * D * sizeof(ushort));
    ushort* uB_bf   = (ushort*)take((size_t)U * D * sizeof(ushort));
    ushort* uC_bf   = (ushort*)take((size_t)U * D * sizeof(ushort));

    // ---- CSR build: partition histogram -> scan -> partition scatter -> bucket finalize ----
    p1_hist<<<NBLK_P, 1024, 0, stream>>>(social_rows, inter_rows, hmat, ES, EI, U, CB, EPB);
    const int nb = (NH + 2047) / 2048;
    scan_partial<<<nb, 256, 0, stream>>>(hmat, hS, bsums, NH);
    scan_top<<<1, 1, 0, stream>>>(bsums, nb);
    scan_add<<<(NH + 255) / 256, 256, 0, stream>>>(hS, bsums, NH);
    p2_scatter<<<NBLK_P, 1024, 0, stream>>>(
        social_rows, social_cols, social_vals,
        inter_rows, inter_cols, inter_vals,
        hS, bedges, ES, EI, U, CB, EPB);
    p3_fin<<<CB, 256, 0, stream>>>(bedges, hS, row_ptr, edges, n2, Etot, CB);

    // ---- bf16 conversions (item half also emits the fp32 passthrough output) ----
    const int u8 = U * D / 8, i8 = I * D / 8;
    f32_to_bf16_2<<<(u8 + i8 + 255) / 256, 256, 0, stream>>>(
        user_emb, ubf, u8, item_emb, ibf, out_item, i8);
    const int nw = L * 2 * D * D;
    conv_w<<<(nw + 255) / 256, 256, 0, stream>>>(weights, wtb, nw);

    // ---- layers ----
    const int spmm_grid = ((U * 8) + 255) / 256;
    const int gemm_grid = (U + 63) / 64;
    const ushort* uprev = ubf;
    int which = 0;
    for (int k = 0; k < L; ++k) {
        const ushort* wk = wtb + (size_t)k * 2 * D * D;
        spmm_g<0><<<spmm_grid, 256, 0, stream>>>(
            row_ptr, edges, uprev, tmpA_bf, (float*)nullptr, U);
        if (k == L - 1) {
            gemm_mfma<true><<<gemm_grid, 256, 0, stream>>>(
                tmpA_bf, uprev, wk, out, (ushort*)nullptr, U);
        } else {
            ushort* unext = which ? uC_bf : uB_bf;
            gemm_mfma<false><<<gemm_grid, 256, 0, stream>>>(
                tmpA_bf, uprev, wk, (float*)nullptr, unext, U);
            uprev = unext;
            which ^= 1;
        }
    }

    // final_u += A_inter @ item_emb (bf16 gather, fp32 accumulate into d_out)
    spmm_g<1><<<spmm_grid, 256, 0, stream>>>(
        row_ptr + U, edges, ibf, (ushort*)nullptr, out, U);
}